// Round 9
// baseline (126.985 us; speedup 1.0000x reference)
//
#include <hip/hip_runtime.h>
#include <math.h>

#define B_ 8
#define NL 64
#define NR 512
#define FD 128
#define HID 128
#define KM 10
#define P_ 262144
#define M_ 131072
#define LDH 136   // padded LDS row stride in bf16 elems (272B, breaks bank conflicts)

typedef short bf16x8 __attribute__((ext_vector_type(8)));
typedef float f32x4 __attribute__((ext_vector_type(4)));

static __device__ __forceinline__ ushort f2bf(float x) {
    union { float f; unsigned int u; } v; v.f = x;
    unsigned int r = v.u + 0x7FFFu + ((v.u >> 16) & 1u);
    return (ushort)(r >> 16);
}
static __device__ __forceinline__ float bf2f(ushort s) {
    union { unsigned int u; float f; } v; v.u = ((unsigned int)s) << 16;
    return v.f;
}
static __device__ __forceinline__ float elu1(float x) {
    return x > 0.f ? x : (__expf(x) - 1.f);
}

// ---------------- k0: pre-swizzle weights into MFMA B-fragment order ----------------
// fragment q = ni*4+ks, elem: wB[(q*64+lane)*8 + j] = Wc1[k][n], n=ni*16+(lane&15), k=ks*32+(lane>>4)*8+j
__global__ __launch_bounds__(256) void k0_prep(const float* __restrict__ Wc1,
        const float* __restrict__ Wpi, const float* __restrict__ Wsig, const float* __restrict__ Wmu,
        ushort* __restrict__ wB, ushort* __restrict__ wBg) {
    int t = threadIdx.x;
    for (int idx = t; idx < 16384; idx += 256) {
        int j = idx & 7, lane = (idx >> 3) & 63, ks = (idx >> 9) & 3, ni = idx >> 11;
        int lrow = lane & 15, kgrp = lane >> 4;
        int n = ni * 16 + lrow, k = ks * 32 + kgrp * 8 + j;
        wB[idx] = f2bf(Wc1[k * HID + n]);
    }
    for (int idx = t; idx < 4096; idx += 256) {
        int j = idx & 7, lane = (idx >> 3) & 63, ks = (idx >> 9) & 3, ni = (idx >> 11) & 1;
        int lrow = lane & 15, kgrp = lane >> 4;
        int n = ni * 16 + lrow, k = ks * 32 + kgrp * 8 + j;
        float wv = 0.f;
        if (n < 10) wv = Wpi[k * KM + n];
        else if (n < 20) wv = Wsig[k * KM + (n - 10)];
        else if (n < 30) wv = Wmu[k * KM + (n - 20)];
        wBg[idx] = f2bf(wv);
    }
}

// ---------------- k1: U = flig @ W1_top + b1 ; V = frec @ W1_bot ; emit col partials ----------------
__global__ __launch_bounds__(128) void k1_uv(const float* __restrict__ flig,
        const float* __restrict__ frec, const float* __restrict__ W1,
        const float* __restrict__ b1, float* __restrict__ U, float* __restrict__ V,
        float* __restrict__ partS, float* __restrict__ partS2) {
    __shared__ float fr[8][128];
    int bid = blockIdx.x, c = threadIdx.x;
    const float* feat; const float* Wb; float* outp; float bias;
    if (bid < 64) {
        int rowbase = bid * 8;
        feat = flig + rowbase * FD; Wb = W1; outp = U + rowbase * HID; bias = b1[c];
    } else {
        int rowbase = (bid - 64) * 8;
        feat = frec + rowbase * FD; Wb = W1 + FD * HID; outp = V + rowbase * HID; bias = 0.f;
    }
    #pragma unroll
    for (int rr = 0; rr < 8; rr++) fr[rr][c] = feat[rr * FD + c];
    __syncthreads();
    float acc[8];
    #pragma unroll
    for (int rr = 0; rr < 8; rr++) acc[rr] = bias;
    #pragma unroll 4
    for (int k = 0; k < FD; k++) {
        float wv = Wb[k * HID + c];
        #pragma unroll
        for (int rr = 0; rr < 8; rr++) acc[rr] += fr[rr][k] * wv;
    }
    float su = 0.f, su2 = 0.f;
    #pragma unroll
    for (int rr = 0; rr < 8; rr++) {
        outp[rr * HID + c] = acc[rr];
        su += acc[rr]; su2 += acc[rr] * acc[rr];
    }
    partS[bid * 128 + c] = su;
    partS2[bid * 128 + c] = su2;
}

// ---------------- k2a: per-batch reduce of partials ----------------
__global__ __launch_bounds__(256) void k2a(const float* __restrict__ partS, const float* __restrict__ partS2,
        float* __restrict__ SU, float* __restrict__ SU2, float* __restrict__ SV, float* __restrict__ SV2) {
    int b = blockIdx.x, t = threadIdx.x, c = t & 127, half = t >> 7;
    if (half == 0) {
        float s = 0.f, s2 = 0.f;
        #pragma unroll
        for (int j = 0; j < 8; j++) { int row = b * 8 + j; s += partS[row * 128 + c]; s2 += partS2[row * 128 + c]; }
        SU[b * 128 + c] = s; SU2[b * 128 + c] = s2;
    } else {
        float s = 0.f, s2 = 0.f;
        for (int j = 0; j < 64; j++) { int row = 64 + b * 64 + j; s += partS[row * 128 + c]; s2 += partS2[row * 128 + c]; }
        SV[b * 128 + c] = s; SV2[b * 128 + c] = s2;
    }
}

// ---------------- k2b: finalize BN1 scale/shift ----------------
__global__ __launch_bounds__(128) void k2b(const float* __restrict__ SU, const float* __restrict__ SU2,
        const float* __restrict__ SV, const float* __restrict__ SV2,
        const float* __restrict__ g1, const float* __restrict__ beta1,
        float* __restrict__ scale1, float* __restrict__ shift1) {
    int c = threadIdx.x;
    float sum = 0.f, ssq = 0.f;
    #pragma unroll
    for (int b = 0; b < B_; b++) {
        float su = SU[b * 128 + c], sv = SV[b * 128 + c];
        sum += (float)NR * su + (float)NL * sv;
        ssq += (float)NR * SU2[b * 128 + c] + 2.f * su * sv + (float)NL * SV2[b * 128 + c];
    }
    float inv = 1.f / (float)P_;
    float mean = sum * inv;
    float var = ssq * inv - mean * mean;
    float sc = g1[c] * rsqrtf(var + 1e-5f);
    scale1[c] = sc; shift1[c] = beta1[c] - mean * sc;
}

// ---------------- k3: persistent double-buffered GEMM — 1 barrier/tile, B in registers ----------------
// grid 512: block bid owns lig row bl=bid, 4 tiles of 128 pairs. Wave w owns cols w*32..w*32+31.
// z layout: z[tile][ni][reg][lane][m]  (ni=w*2+nil; m packed in bf16x8)
__global__ __launch_bounds__(256, 2) void k3_gemm(const float* __restrict__ U, const float* __restrict__ V,
        const ushort* __restrict__ wB, const float* __restrict__ bc1,
        const float* __restrict__ scale1, const float* __restrict__ shift1,
        ushort* __restrict__ z, float* __restrict__ bn2s, float* __restrict__ bn2s2) {
    __shared__ ushort hA[128 * LDH];     // 34816 B
    __shared__ ushort hB[128 * LDH];     // 34816 B -> 69.6 KB => 2 blocks/CU
    int bid = blockIdx.x, t = threadIdx.x;
    int bl = bid;
    int w = t >> 6, lane = t & 63, lrow = lane & 15, kgrp = lane >> 4;
    // B fragments for this wave's 32 columns: loaded once, held in 32 VGPRs
    const bf16x8* wBv = (const bf16x8*)wB;
    bf16x8 Bfr[2][4];
    #pragma unroll
    for (int nil = 0; nil < 2; nil++)
        #pragma unroll
        for (int ks = 0; ks < 4; ks++)
            Bfr[nil][ks] = wBv[((w * 2 + nil) * 4 + ks) * 64 + lane];
    float bc1v[2] = { bc1[w * 32 + lrow], bc1[w * 32 + 16 + lrow] };
    float s[2] = {0.f, 0.f}, s2[2] = {0.f, 0.f};
    int c8 = (t & 15) * 8, rg = t >> 4;
    float4 sc0 = *(const float4*)&scale1[c8], sc1 = *(const float4*)&scale1[c8 + 4];
    float4 sh0 = *(const float4*)&shift1[c8], sh1 = *(const float4*)&shift1[c8 + 4];
    float4 u0 = *(const float4*)&U[bl * HID + c8];
    float4 u1 = *(const float4*)&U[bl * HID + c8 + 4];
    // fold U into the shift: h = elu(v*sc + ub)
    float4 ub0, ub1;
    ub0.x = fmaf(u0.x, sc0.x, sh0.x); ub0.y = fmaf(u0.y, sc0.y, sh0.y);
    ub0.z = fmaf(u0.z, sc0.z, sh0.z); ub0.w = fmaf(u0.w, sc0.w, sh0.w);
    ub1.x = fmaf(u1.x, sc1.x, sh1.x); ub1.y = fmaf(u1.y, sc1.y, sh1.y);
    ub1.z = fmaf(u1.z, sc1.z, sh1.z); ub1.w = fmaf(u1.w, sc1.w, sh1.w);
    int vbatch = (bl >> 6) << 9;

    auto STAGE = [&](ushort* buf, int it) {
        int vtile = vbatch + it * 128;
        #pragma unroll
        for (int rr = rg; rr < 128; rr += 16) {
            const float* vp = &V[(vtile + rr) * HID + c8];
            float4 v0 = *(const float4*)vp, v1 = *(const float4*)(vp + 4);
            union { bf16x8 v; ushort u[8]; } o;
            o.u[0] = f2bf(elu1(fmaf(v0.x, sc0.x, ub0.x)));
            o.u[1] = f2bf(elu1(fmaf(v0.y, sc0.y, ub0.y)));
            o.u[2] = f2bf(elu1(fmaf(v0.z, sc0.z, ub0.z)));
            o.u[3] = f2bf(elu1(fmaf(v0.w, sc0.w, ub0.w)));
            o.u[4] = f2bf(elu1(fmaf(v1.x, sc1.x, ub1.x)));
            o.u[5] = f2bf(elu1(fmaf(v1.y, sc1.y, ub1.y)));
            o.u[6] = f2bf(elu1(fmaf(v1.z, sc1.z, ub1.z)));
            o.u[7] = f2bf(elu1(fmaf(v1.w, sc1.w, ub1.w)));
            *(bf16x8*)&buf[rr * LDH + c8] = o.v;
        }
    };
    auto COMPUTE = [&](const ushort* buf, int it) {
        int tile = bl * 4 + it;
        f32x4 acc[8][2];
        #pragma unroll
        for (int m = 0; m < 8; m++) { acc[m][0] = (f32x4){0,0,0,0}; acc[m][1] = (f32x4){0,0,0,0}; }
        #pragma unroll
        for (int m = 0; m < 8; m++) {
            #pragma unroll
            for (int ks = 0; ks < 4; ks++) {
                bf16x8 a = *(const bf16x8*)&buf[(m * 16 + lrow) * LDH + ks * 32 + kgrp * 8];
                acc[m][0] = __builtin_amdgcn_mfma_f32_16x16x32_bf16(a, Bfr[0][ks], acc[m][0], 0, 0, 0);
                acc[m][1] = __builtin_amdgcn_mfma_f32_16x16x32_bf16(a, Bfr[1][ks], acc[m][1], 0, 0, 0);
            }
        }
        #pragma unroll
        for (int nil = 0; nil < 2; nil++)
            #pragma unroll
            for (int reg = 0; reg < 4; reg++) {
                union { bf16x8 v; ushort u[8]; } o;
                #pragma unroll
                for (int m = 0; m < 8; m++) {
                    float vv = acc[m][nil][reg] + bc1v[nil];
                    s[nil] += vv; s2[nil] += vv * vv;
                    o.u[m] = f2bf(vv);
                }
                *(bf16x8*)&z[(((tile * 8 + w * 2 + nil) * 4 + reg) * 64 + lane) * 8] = o.v;
            }
    };

    STAGE(hA, 0);
    __syncthreads();
    STAGE(hB, 1); COMPUTE(hA, 0); __syncthreads();
    STAGE(hA, 2); COMPUTE(hB, 1); __syncthreads();
    STAGE(hB, 3); COMPUTE(hA, 2); __syncthreads();
    COMPUTE(hB, 3);

    // wave-local column stats: sum over kgrp lanes (16/32 apart)
    #pragma unroll
    for (int nil = 0; nil < 2; nil++) {
        s[nil] += __shfl_xor(s[nil], 16);  s[nil] += __shfl_xor(s[nil], 32);
        s2[nil] += __shfl_xor(s2[nil], 16); s2[nil] += __shfl_xor(s2[nil], 32);
    }
    if (lane < 16) {
        bn2s[bid * 128 + w * 32 + lane]       = s[0];
        bn2s[bid * 128 + w * 32 + 16 + lane]  = s[1];
        bn2s2[bid * 128 + w * 32 + lane]      = s2[0];
        bn2s2[bid * 128 + w * 32 + 16 + lane] = s2[1];
    }
}

// ---------------- k4a/k4b: reduce BN2 partials (512 rows) -> epilogue params ----------------
__global__ __launch_bounds__(256) void k4a(const float* __restrict__ bn2s, const float* __restrict__ bn2s2,
        float* __restrict__ l2s, float* __restrict__ l2s2) {
    int j = blockIdx.x, t = threadIdx.x, c = t & 127, half = t >> 7;
    float s = 0, s2 = 0;
    #pragma unroll
    for (int rr = half; rr < 8; rr += 2) {
        int row = j * 8 + rr;
        s += bn2s[row * 128 + c]; s2 += bn2s2[row * 128 + c];
    }
    __shared__ float red[2][2][128];
    red[0][half][c] = s; red[1][half][c] = s2;
    __syncthreads();
    if (t < 128) { l2s[j * 128 + t] = red[0][0][t] + red[0][1][t]; l2s2[j * 128 + t] = red[1][0][t] + red[1][1][t]; }
}

__global__ __launch_bounds__(128) void k4b(const float* __restrict__ l2s, const float* __restrict__ l2s2,
        const float* __restrict__ gc, const float* __restrict__ betac,
        float* __restrict__ Af, float* __restrict__ Bf) {
    int c = threadIdx.x;
    float s = 0, s2 = 0;
    #pragma unroll
    for (int j = 0; j < 64; j++) { s += l2s[j * 128 + c]; s2 += l2s2[j * 128 + c]; }
    float inv = 1.f / (float)P_;
    float mean = s * inv, var = s2 * inv - mean * mean;
    float sc = gc[c] * rsqrtf(var + 1e-5f);
    Af[c] = sc;
    Bf[c] = betac[c] - mean * sc;   // z already contains bc1
}

// ---------------- k5: streaming contact epilogue over fragment-order z ----------------
// mirrors k3's z layout: z[tile][ni][reg][lane][m]; cross-wave LDS reduce for the 128-col dot
__global__ __launch_bounds__(256) void k5_contact(const ushort* __restrict__ z,
        const float* __restrict__ Af, const float* __restrict__ Bf,
        const float* __restrict__ Wc2, const float* __restrict__ bc2,
        const float* __restrict__ posl, const float* __restrict__ posr,
        float* __restrict__ outc, float* __restrict__ outt) {
    __shared__ float part[4][128];
    int bid = blockIdx.x, t = threadIdx.x;   // bid = tile
    int w = t >> 6, lane = t & 63, lrow = lane & 15, kgrp = lane >> 4;
    float av[2], bv[2], wv[2];
    #pragma unroll
    for (int nil = 0; nil < 2; nil++) {
        int c = w * 32 + nil * 16 + lrow;
        av[nil] = Af[c]; bv[nil] = Bf[c]; wv[nil] = Wc2[c];
    }
    float bc2v = bc2[0];
    #pragma unroll
    for (int reg = 0; reg < 4; reg++) {
        float pr[8];
        #pragma unroll
        for (int m = 0; m < 8; m++) pr[m] = 0.f;
        #pragma unroll
        for (int nil = 0; nil < 2; nil++) {
            bf16x8 zv = *(const bf16x8*)&z[(((bid * 8 + w * 2 + nil) * 4 + reg) * 64 + lane) * 8];
            #pragma unroll
            for (int m = 0; m < 8; m++) {
                float x = fmaf(bf2f((ushort)zv[m]), av[nil], bv[nil]);
                pr[m] += fmaxf(x, 0.f) * wv[nil];
            }
        }
        #pragma unroll
        for (int m = 0; m < 8; m++) {
            pr[m] += __shfl_xor(pr[m], 1); pr[m] += __shfl_xor(pr[m], 2);
            pr[m] += __shfl_xor(pr[m], 4); pr[m] += __shfl_xor(pr[m], 8);
        }
        if (lrow == 0) {
            #pragma unroll
            for (int m = 0; m < 8; m++) part[w][m * 16 + kgrp * 4 + reg] = pr[m];
        }
    }
    __syncthreads();
    if (t < 128) {
        int row = bid * 128 + t;
        outc[row] = part[0][t] + part[1][t] + part[2][t] + part[3][t] + bc2v;
        int bl = row >> 9, b = row >> 15, r = row & 511;
        float dx = posl[bl * 3]     - posr[(b * NR + r) * 3];
        float dy = posl[bl * 3 + 1] - posr[(b * NR + r) * 3 + 1];
        float dz = posl[bl * 3 + 2] - posr[(b * NR + r) * 3 + 2];
        float y = sqrtf(dx * dx + dy * dy + dz * dz);
        outt[row] = (y < 8.0f) ? 1.0f : 0.0f;
    }
}

// ---------------- k6: MDN (gather h via U+V recompute, 128x32 MFMA, coalesced outputs) ----------------
__global__ __launch_bounds__(256) void k6_mdn(const int* __restrict__ mask,
        const float* __restrict__ U, const float* __restrict__ V,
        const float* __restrict__ scale1, const float* __restrict__ shift1,
        const ushort* __restrict__ wBg,
        const float* __restrict__ bpi, const float* __restrict__ bsig, const float* __restrict__ bmu,
        const float* __restrict__ posl, const float* __restrict__ posr,
        float* __restrict__ out_logpi, float* __restrict__ out_sigma, float* __restrict__ out_mu,
        float* __restrict__ mdn_psum, float* __restrict__ mdn_pcnt) {
    __shared__ ushort hT[128 * LDH];
    float* stageF = (float*)hT;                 // aliased scratch (barriers guard reuse)
    float* zl   = stageF;                        // 128*33 = 4224 floats
    float* bufA = stageF + 4352;                 // 1280 floats (16B aligned)
    float* bufB = stageF + 4352 + 1280;
    float* bufC = stageF + 4352 + 2560;          // ends at 8192 floats = 32768B < 34816B
    __shared__ int midx[128];
    __shared__ float mdnv[128];
    __shared__ int mdnb[128];
    int bid = blockIdx.x, t = threadIdx.x;
    int m0 = bid * 128;
    if (t < 128) midx[t] = mask[m0 + t];
    __syncthreads();
    {
        int c8 = (t & 15) * 8, rg = t >> 4;
        float4 sc0 = *(const float4*)&scale1[c8], sc1 = *(const float4*)&scale1[c8 + 4];
        float4 sh0 = *(const float4*)&shift1[c8], sh1 = *(const float4*)&shift1[c8 + 4];
        #pragma unroll
        for (int rr = rg; rr < 128; rr += 16) {
            int i = midx[rr];
            int bl = i >> 9, b = i >> 15, r = i & 511;
            const float* up = &U[bl * HID + c8];
            const float* vp = &V[(b * NR + r) * HID + c8];
            float4 u0 = *(const float4*)up, u1 = *(const float4*)(up + 4);
            float4 v0 = *(const float4*)vp, v1 = *(const float4*)(vp + 4);
            union { bf16x8 v; ushort u[8]; } o;
            o.u[0] = f2bf(elu1(fmaf(u0.x + v0.x, sc0.x, sh0.x)));
            o.u[1] = f2bf(elu1(fmaf(u0.y + v0.y, sc0.y, sh0.y)));
            o.u[2] = f2bf(elu1(fmaf(u0.z + v0.z, sc0.z, sh0.z)));
            o.u[3] = f2bf(elu1(fmaf(u0.w + v0.w, sc0.w, sh0.w)));
            o.u[4] = f2bf(elu1(fmaf(u1.x + v1.x, sc1.x, sh1.x)));
            o.u[5] = f2bf(elu1(fmaf(u1.y + v1.y, sc1.y, sh1.y)));
            o.u[6] = f2bf(elu1(fmaf(u1.z + v1.z, sc1.z, sh1.z)));
            o.u[7] = f2bf(elu1(fmaf(u1.w + v1.w, sc1.w, sh1.w)));
            *(bf16x8*)&hT[rr * LDH + c8] = o.v;
        }
    }
    __syncthreads();
    int w = t >> 6, lane = t & 63;
    int wrow = w * 32, lrow = lane & 15, kgrp = lane >> 4;
    f32x4 acc[2][2];
    #pragma unroll
    for (int mi = 0; mi < 2; mi++)
        #pragma unroll
        for (int ni = 0; ni < 2; ni++) acc[mi][ni] = (f32x4){0.f, 0.f, 0.f, 0.f};
    const bf16x8* wBv = (const bf16x8*)wBg;
    #pragma unroll
    for (int ks = 0; ks < 4; ks++) {
        int ko = ks * 32 + kgrp * 8;
        bf16x8 a0 = *(const bf16x8*)&hT[(wrow + lrow) * LDH + ko];
        bf16x8 a1 = *(const bf16x8*)&hT[(wrow + 16 + lrow) * LDH + ko];
        bf16x8 b0 = wBv[ks * 64 + lane];
        bf16x8 b1 = wBv[(4 + ks) * 64 + lane];
        acc[0][0] = __builtin_amdgcn_mfma_f32_16x16x32_bf16(a0, b0, acc[0][0], 0, 0, 0);
        acc[0][1] = __builtin_amdgcn_mfma_f32_16x16x32_bf16(a0, b1, acc[0][1], 0, 0, 0);
        acc[1][0] = __builtin_amdgcn_mfma_f32_16x16x32_bf16(a1, b0, acc[1][0], 0, 0, 0);
        acc[1][1] = __builtin_amdgcn_mfma_f32_16x16x32_bf16(a1, b1, acc[1][1], 0, 0, 0);
    }
    __syncthreads();   // all hT reads done before zl alias writes
    #pragma unroll
    for (int mi = 0; mi < 2; mi++)
        #pragma unroll
        for (int ni = 0; ni < 2; ni++)
            #pragma unroll
            for (int reg = 0; reg < 4; reg++) {
                int row = wrow + mi * 16 + kgrp * 4 + reg;
                zl[row * 33 + ni * 16 + lrow] = acc[mi][ni][reg];
            }
    __syncthreads();
    if (t < 128) {
        float zv[30];
        #pragma unroll
        for (int j = 0; j < 30; j++) zv[j] = zl[t * 33 + j];
        float lp[10], mx = -1e30f;
        #pragma unroll
        for (int j = 0; j < 10; j++) { lp[j] = zv[j] + bpi[j]; mx = fmaxf(mx, lp[j]); }
        float se = 0.f;
        #pragma unroll
        for (int j = 0; j < 10; j++) se += __expf(lp[j] - mx);
        float lse = mx + __logf(se);
        #pragma unroll
        for (int j = 0; j < 10; j++) lp[j] -= lse;
        float sg[10], muv[10];
        #pragma unroll
        for (int j = 0; j < 10; j++) sg[j] = elu1(zv[10 + j] + bsig[j]) + 1.1f;
        #pragma unroll
        for (int j = 0; j < 10; j++) muv[j] = elu1(zv[20 + j] + bmu[j]) + 1.0f;
        int i = midx[t];
        int bl = i >> 9, b = i >> 15, r = i & 511;
        float dx = posl[bl * 3]     - posr[(b * NR + r) * 3];
        float dy = posl[bl * 3 + 1] - posr[(b * NR + r) * 3 + 1];
        float dz = posl[bl * 3 + 2] - posr[(b * NR + r) * 3 + 2];
        float y = sqrtf(dx * dx + dy * dy + dz * dz);
        float tt[10], mm = -1e30f;
        #pragma unroll
        for (int j = 0; j < 10; j++) {
            float q = (y - muv[j]) / sg[j];
            float llv = -0.5f * q * q - __logf(sg[j]) - 0.91893853320467274f;
            tt[j] = lp[j] + llv; mm = fmaxf(mm, tt[j]);
        }
        float s2e = 0.f;
        #pragma unroll
        for (int j = 0; j < 10; j++) s2e += __expf(tt[j] - mm);
        float mdn = -(mm + __logf(s2e));
        #pragma unroll
        for (int j = 0; j < 10; j++) { bufA[t * 10 + j] = lp[j]; bufB[t * 10 + j] = sg[j]; bufC[t * 10 + j] = muv[j]; }
        mdnv[t] = mdn; mdnb[t] = b;
    }
    __syncthreads();
    // coalesced float4 copy-out: 320 float4 per array
    {
        float4* oA = (float4*)&out_logpi[m0 * 10];
        float4* oB = (float4*)&out_sigma[m0 * 10];
        float4* oC = (float4*)&out_mu[m0 * 10];
        const float4* bA = (const float4*)bufA;
        const float4* bB = (const float4*)bufB;
        const float4* bC = (const float4*)bufC;
        #pragma unroll
        for (int i4 = t; i4 < 320; i4 += 256) { oA[i4] = bA[i4]; oB[i4] = bB[i4]; oC[i4] = bC[i4]; }
    }
    if (t < 8) {  // deterministic fixed-order per-batch partial sums
        float s = 0.f; int cnt = 0;
        for (int rr = 0; rr < 128; rr++) if (mdnb[rr] == t) { s += mdnv[rr]; cnt++; }
        mdn_psum[bid * 8 + t] = s; mdn_pcnt[bid * 8 + t] = (float)cnt;
    }
}

// ---------------- k7: prob = segment mean ----------------
__global__ __launch_bounds__(256) void k7_prob(const float* __restrict__ psum, const float* __restrict__ pcnt,
        float* __restrict__ prob) {
    int b = blockIdx.x, t = threadIdx.x;
    float s = 0, c = 0;
    for (int idx = t; idx < 1024; idx += 256) { s += psum[idx * 8 + b]; c += pcnt[idx * 8 + b]; }
    __shared__ float rs[256], rc[256];
    rs[t] = s; rc[t] = c;
    __syncthreads();
    for (int off = 128; off > 0; off >>= 1) {
        if (t < off) { rs[t] += rs[t + off]; rc[t] += rc[t + off]; }
        __syncthreads();
    }
    if (t == 0) prob[b] = rs[0] / fmaxf(rc[0], 1.f);
}

extern "C" void kernel_launch(void* const* d_in, const int* in_sizes, int n_in,
                              void* d_out, int out_size, void* d_ws, size_t ws_size,
                              hipStream_t stream) {
    const float* flig  = (const float*)d_in[0];
    const float* posl  = (const float*)d_in[1];
    const float* frec  = (const float*)d_in[3];
    const float* posr  = (const float*)d_in[4];
    const int*   mask  = (const int*)d_in[6];
    const float* W1    = (const float*)d_in[7];
    const float* b1    = (const float*)d_in[8];
    const float* g1    = (const float*)d_in[9];
    const float* beta1 = (const float*)d_in[10];
    const float* Wpi   = (const float*)d_in[11];
    const float* bpi   = (const float*)d_in[12];
    const float* Wsig  = (const float*)d_in[13];
    const float* bsig  = (const float*)d_in[14];
    const float* Wmu   = (const float*)d_in[15];
    const float* bmu   = (const float*)d_in[16];
    const float* Wc1   = (const float*)d_in[17];
    const float* bc1   = (const float*)d_in[18];
    const float* gc    = (const float*)d_in[19];
    const float* betac = (const float*)d_in[20];
    const float* Wc2   = (const float*)d_in[21];
    const float* bc2   = (const float*)d_in[22];

    float* ws = (float*)d_ws;
    float* U      = ws;                 // 65536
    float* V      = ws + 65536;         // 524288 (end 589824)
    float* scale1 = ws + 589824;        // 128
    float* shift1 = ws + 589952;
    float* Af     = ws + 590080;
    float* Bf     = ws + 590208;        // (end 590336)
    float* SU     = ws + 590336;        // 1024
    float* SU2    = ws + 591360;
    float* SV     = ws + 592384;
    float* SV2    = ws + 593408;        // (end 594432)
    ushort* wB    = (ushort*)(ws + 594432);   // 16384 bf16 (end 602624)
    ushort* wBg   = (ushort*)(ws + 602624);   // 4096 bf16 (end 604672)
    float* bn2s   = ws + 604672;        // 512*128 (end 670208)
    float* bn2s2  = ws + 670208;        // (end 735744)
    float* psum   = ws + 735744;        // 8192 (end 743936)
    float* pcnt   = ws + 743936;        // (end 752128)
    ushort* zbuf  = (ushort*)(ws + 752128);   // P*128 bf16 = 67.1 MB (fragment order)
    // partS/partS2 alias zbuf region: dead before k3 writes z (stream-ordered)
    float* partS  = ws + 752128;        // 576*128
    float* partS2 = ws + 825856;        // (end 899584)
    // l2s/l2s2 share psum/pcnt: lifetimes [k4a..k4b] vs [k6..k7] are disjoint
    float* l2s1_  = psum;
    float* l2s2_  = pcnt;

    float* out = (float*)d_out;
    float* out_logpi   = out;
    float* out_sigma   = out + 1310720;
    float* out_mu      = out + 2621440;
    float* out_prob    = out + 3932160;
    float* out_contact = out + 3932168;
    float* out_truth   = out + 4194312;

    k0_prep<<<dim3(1), dim3(256), 0, stream>>>(Wc1, Wpi, Wsig, Wmu, wB, wBg);
    k1_uv<<<dim3(576), dim3(128), 0, stream>>>(flig, frec, W1, b1, U, V, partS, partS2);
    k2a<<<dim3(8), dim3(256), 0, stream>>>(partS, partS2, SU, SU2, SV, SV2);
    k2b<<<dim3(1), dim3(128), 0, stream>>>(SU, SU2, SV, SV2, g1, beta1, scale1, shift1);
    k3_gemm<<<dim3(512), dim3(256), 0, stream>>>(U, V, wB, bc1, scale1, shift1, zbuf, bn2s, bn2s2);
    k4a<<<dim3(64), dim3(256), 0, stream>>>(bn2s, bn2s2, l2s1_, l2s2_);
    k4b<<<dim3(1), dim3(128), 0, stream>>>(l2s1_, l2s2_, gc, betac, Af, Bf);
    k5_contact<<<dim3(2048), dim3(256), 0, stream>>>(zbuf, Af, Bf, Wc2, bc2, posl, posr, out_contact, out_truth);
    k6_mdn<<<dim3(1024), dim3(256), 0, stream>>>(mask, U, V, scale1, shift1, wBg,
        bpi, bsig, bmu, posl, posr, out_logpi, out_sigma, out_mu, psum, pcnt);
    k7_prob<<<dim3(8), dim3(256), 0, stream>>>(psum, pcnt, out_prob);
}

// Round 10
// 105.827 us; speedup vs baseline: 1.1999x; 1.1999x over previous
//
#include <hip/hip_runtime.h>
#include <math.h>

#define B_ 8
#define NL 64
#define NR 512
#define FD 128
#define HID 128
#define KM 10
#define P_ 262144
#define NSAMP 32768
#define M_ 131072
#define LDH 136   // padded LDS row stride in bf16 elems (272B, breaks bank conflicts)

typedef short bf16x8 __attribute__((ext_vector_type(8)));
typedef float f32x4 __attribute__((ext_vector_type(4)));

static __device__ __forceinline__ ushort f2bf(float x) {
    union { float f; unsigned int u; } v; v.f = x;
    unsigned int r = v.u + 0x7FFFu + ((v.u >> 16) & 1u);
    return (ushort)(r >> 16);
}
static __device__ __forceinline__ float elu1(float x) {
    return x > 0.f ? x : (__expf(x) - 1.f);
}

// ---------------- k0: pre-swizzle weights into MFMA B-fragment order ----------------
__global__ __launch_bounds__(256) void k0_prep(const float* __restrict__ Wc1,
        const float* __restrict__ Wpi, const float* __restrict__ Wsig, const float* __restrict__ Wmu,
        ushort* __restrict__ wB, ushort* __restrict__ wBg) {
    int t = threadIdx.x;
    for (int idx = t; idx < 16384; idx += 256) {
        int j = idx & 7, lane = (idx >> 3) & 63, ks = (idx >> 9) & 3, ni = idx >> 11;
        int lrow = lane & 15, kgrp = lane >> 4;
        int n = ni * 16 + lrow, k = ks * 32 + kgrp * 8 + j;
        wB[idx] = f2bf(Wc1[k * HID + n]);
    }
    for (int idx = t; idx < 4096; idx += 256) {
        int j = idx & 7, lane = (idx >> 3) & 63, ks = (idx >> 9) & 3, ni = (idx >> 11) & 1;
        int lrow = lane & 15, kgrp = lane >> 4;
        int n = ni * 16 + lrow, k = ks * 32 + kgrp * 8 + j;
        float wv = 0.f;
        if (n < 10) wv = Wpi[k * KM + n];
        else if (n < 20) wv = Wsig[k * KM + (n - 10)];
        else if (n < 30) wv = Wmu[k * KM + (n - 20)];
        wBg[idx] = f2bf(wv);
    }
}

// ---------------- k1: U = flig @ W1_top + b1 ; V = frec @ W1_bot ; emit col partials ----------------
__global__ __launch_bounds__(128) void k1_uv(const float* __restrict__ flig,
        const float* __restrict__ frec, const float* __restrict__ W1,
        const float* __restrict__ b1, float* __restrict__ U, float* __restrict__ V,
        float* __restrict__ partS, float* __restrict__ partS2) {
    __shared__ float fr[8][128];
    int bid = blockIdx.x, c = threadIdx.x;
    const float* feat; const float* Wb; float* outp; float bias;
    if (bid < 64) {
        int rowbase = bid * 8;
        feat = flig + rowbase * FD; Wb = W1; outp = U + rowbase * HID; bias = b1[c];
    } else {
        int rowbase = (bid - 64) * 8;
        feat = frec + rowbase * FD; Wb = W1 + FD * HID; outp = V + rowbase * HID; bias = 0.f;
    }
    #pragma unroll
    for (int rr = 0; rr < 8; rr++) fr[rr][c] = feat[rr * FD + c];
    __syncthreads();
    float acc[8];
    #pragma unroll
    for (int rr = 0; rr < 8; rr++) acc[rr] = bias;
    #pragma unroll 4
    for (int k = 0; k < FD; k++) {
        float wv = Wb[k * HID + c];
        #pragma unroll
        for (int rr = 0; rr < 8; rr++) acc[rr] += fr[rr][k] * wv;
    }
    float su = 0.f, su2 = 0.f;
    #pragma unroll
    for (int rr = 0; rr < 8; rr++) {
        outp[rr * HID + c] = acc[rr];
        su += acc[rr]; su2 += acc[rr] * acc[rr];
    }
    partS[bid * 128 + c] = su;
    partS2[bid * 128 + c] = su2;
}

// ---------------- k2a: per-batch reduce of partials ----------------
__global__ __launch_bounds__(256) void k2a(const float* __restrict__ partS, const float* __restrict__ partS2,
        float* __restrict__ SU, float* __restrict__ SU2, float* __restrict__ SV, float* __restrict__ SV2) {
    int b = blockIdx.x, t = threadIdx.x, c = t & 127, half = t >> 7;
    if (half == 0) {
        float s = 0.f, s2 = 0.f;
        #pragma unroll
        for (int j = 0; j < 8; j++) { int row = b * 8 + j; s += partS[row * 128 + c]; s2 += partS2[row * 128 + c]; }
        SU[b * 128 + c] = s; SU2[b * 128 + c] = s2;
    } else {
        float s = 0.f, s2 = 0.f;
        for (int j = 0; j < 64; j++) { int row = 64 + b * 64 + j; s += partS[row * 128 + c]; s2 += partS2[row * 128 + c]; }
        SV[b * 128 + c] = s; SV2[b * 128 + c] = s2;
    }
}

// ---------------- k2b: finalize BN1 scale/shift ----------------
__global__ __launch_bounds__(128) void k2b(const float* __restrict__ SU, const float* __restrict__ SU2,
        const float* __restrict__ SV, const float* __restrict__ SV2,
        const float* __restrict__ g1, const float* __restrict__ beta1,
        float* __restrict__ scale1, float* __restrict__ shift1) {
    int c = threadIdx.x;
    float sum = 0.f, ssq = 0.f;
    #pragma unroll
    for (int b = 0; b < B_; b++) {
        float su = SU[b * 128 + c], sv = SV[b * 128 + c];
        sum += (float)NR * su + (float)NL * sv;
        ssq += (float)NR * SU2[b * 128 + c] + 2.f * su * sv + (float)NL * SV2[b * 128 + c];
    }
    float inv = 1.f / (float)P_;
    float mean = sum * inv;
    float var = ssq * inv - mean * mean;
    float sc = g1[c] * rsqrtf(var + 1e-5f);
    scale1[c] = sc; shift1[c] = beta1[c] - mean * sc;
}

// ---------------- k3s: SAMPLED BN2 stats — 1/8 stratified (every 8th rec row) ----------------
// grid 256: block bid handles lig rows bl0=2bid, bl1=2bid+1 × 64 sampled recs (r=8j) = 128 pairs.
__global__ __launch_bounds__(256, 2) void k3s_stats(const float* __restrict__ U, const float* __restrict__ V,
        const ushort* __restrict__ wB, const float* __restrict__ bc1,
        const float* __restrict__ scale1, const float* __restrict__ shift1,
        float* __restrict__ bn2s, float* __restrict__ bn2s2) {
    __shared__ ushort hT[128 * LDH];
    int bid = blockIdx.x, t = threadIdx.x;
    int bl0 = bid * 2, bl1 = bl0 + 1;
    int w = t >> 6, lane = t & 63, lrow = lane & 15, kgrp = lane >> 4;
    const bf16x8* wBv = (const bf16x8*)wB;
    bf16x8 Bfr[2][4];
    #pragma unroll
    for (int nil = 0; nil < 2; nil++)
        #pragma unroll
        for (int ks = 0; ks < 4; ks++)
            Bfr[nil][ks] = wBv[((w * 2 + nil) * 4 + ks) * 64 + lane];
    float bc1v[2] = { bc1[w * 32 + lrow], bc1[w * 32 + 16 + lrow] };
    int c8 = (t & 15) * 8, rg = t >> 4;
    float4 sc0 = *(const float4*)&scale1[c8], sc1 = *(const float4*)&scale1[c8 + 4];
    float4 sh0 = *(const float4*)&shift1[c8], sh1 = *(const float4*)&shift1[c8 + 4];
    float4 uA0 = *(const float4*)&U[bl0 * HID + c8], uA1 = *(const float4*)&U[bl0 * HID + c8 + 4];
    float4 uB0 = *(const float4*)&U[bl1 * HID + c8], uB1 = *(const float4*)&U[bl1 * HID + c8 + 4];
    float4 ubA0, ubA1, ubB0, ubB1;
    ubA0.x = fmaf(uA0.x, sc0.x, sh0.x); ubA0.y = fmaf(uA0.y, sc0.y, sh0.y);
    ubA0.z = fmaf(uA0.z, sc0.z, sh0.z); ubA0.w = fmaf(uA0.w, sc0.w, sh0.w);
    ubA1.x = fmaf(uA1.x, sc1.x, sh1.x); ubA1.y = fmaf(uA1.y, sc1.y, sh1.y);
    ubA1.z = fmaf(uA1.z, sc1.z, sh1.z); ubA1.w = fmaf(uA1.w, sc1.w, sh1.w);
    ubB0.x = fmaf(uB0.x, sc0.x, sh0.x); ubB0.y = fmaf(uB0.y, sc0.y, sh0.y);
    ubB0.z = fmaf(uB0.z, sc0.z, sh0.z); ubB0.w = fmaf(uB0.w, sc0.w, sh0.w);
    ubB1.x = fmaf(uB1.x, sc1.x, sh1.x); ubB1.y = fmaf(uB1.y, sc1.y, sh1.y);
    ubB1.z = fmaf(uB1.z, sc1.z, sh1.z); ubB1.w = fmaf(uB1.w, sc1.w, sh1.w);
    int vbatch = (bl0 >> 6) << 9;
    #pragma unroll
    for (int k = 0; k < 8; k++) {
        int rr = rg + k * 16;
        int j = rr & 63;
        const float* vp = &V[(vbatch + j * 8) * HID + c8];
        float4 v0 = *(const float4*)vp, v1 = *(const float4*)(vp + 4);
        float4 ub0 = (k < 4) ? ubA0 : ubB0;
        float4 ub1 = (k < 4) ? ubA1 : ubB1;
        union { bf16x8 v; ushort u[8]; } o;
        o.u[0] = f2bf(elu1(fmaf(v0.x, sc0.x, ub0.x)));
        o.u[1] = f2bf(elu1(fmaf(v0.y, sc0.y, ub0.y)));
        o.u[2] = f2bf(elu1(fmaf(v0.z, sc0.z, ub0.z)));
        o.u[3] = f2bf(elu1(fmaf(v0.w, sc0.w, ub0.w)));
        o.u[4] = f2bf(elu1(fmaf(v1.x, sc1.x, ub1.x)));
        o.u[5] = f2bf(elu1(fmaf(v1.y, sc1.y, ub1.y)));
        o.u[6] = f2bf(elu1(fmaf(v1.z, sc1.z, ub1.z)));
        o.u[7] = f2bf(elu1(fmaf(v1.w, sc1.w, ub1.w)));
        *(bf16x8*)&hT[rr * LDH + c8] = o.v;
    }
    __syncthreads();
    f32x4 acc[8][2];
    #pragma unroll
    for (int m = 0; m < 8; m++) { acc[m][0] = (f32x4){0,0,0,0}; acc[m][1] = (f32x4){0,0,0,0}; }
    #pragma unroll
    for (int m = 0; m < 8; m++) {
        #pragma unroll
        for (int ks = 0; ks < 4; ks++) {
            bf16x8 a = *(const bf16x8*)&hT[(m * 16 + lrow) * LDH + ks * 32 + kgrp * 8];
            acc[m][0] = __builtin_amdgcn_mfma_f32_16x16x32_bf16(a, Bfr[0][ks], acc[m][0], 0, 0, 0);
            acc[m][1] = __builtin_amdgcn_mfma_f32_16x16x32_bf16(a, Bfr[1][ks], acc[m][1], 0, 0, 0);
        }
    }
    float s[2] = {0.f, 0.f}, s2[2] = {0.f, 0.f};
    #pragma unroll
    for (int nil = 0; nil < 2; nil++)
        #pragma unroll
        for (int reg = 0; reg < 4; reg++)
            #pragma unroll
            for (int m = 0; m < 8; m++) {
                float vv = acc[m][nil][reg] + bc1v[nil];
                s[nil] += vv; s2[nil] += vv * vv;
            }
    #pragma unroll
    for (int nil = 0; nil < 2; nil++) {
        s[nil] += __shfl_xor(s[nil], 16);  s[nil] += __shfl_xor(s[nil], 32);
        s2[nil] += __shfl_xor(s2[nil], 16); s2[nil] += __shfl_xor(s2[nil], 32);
    }
    if (lane < 16) {
        bn2s[bid * 128 + w * 32 + lane]       = s[0];
        bn2s[bid * 128 + w * 32 + 16 + lane]  = s[1];
        bn2s2[bid * 128 + w * 32 + lane]      = s2[0];
        bn2s2[bid * 128 + w * 32 + 16 + lane] = s2[1];
    }
}

// ---------------- k4a/k4b: reduce sampled BN2 partials (256 rows) -> fused epilogue params ----------------
__global__ __launch_bounds__(256) void k4a(const float* __restrict__ bn2s, const float* __restrict__ bn2s2,
        float* __restrict__ l2s, float* __restrict__ l2s2) {
    int j = blockIdx.x, t = threadIdx.x, c = t & 127, half = t >> 7;
    float s = 0, s2 = 0;
    #pragma unroll
    for (int rr = half; rr < 8; rr += 2) {
        int row = j * 8 + rr;
        s += bn2s[row * 128 + c]; s2 += bn2s2[row * 128 + c];
    }
    __shared__ float red[2][2][128];
    red[0][half][c] = s; red[1][half][c] = s2;
    __syncthreads();
    if (t < 128) { l2s[j * 128 + t] = red[0][0][t] + red[0][1][t]; l2s2[j * 128 + t] = red[1][0][t] + red[1][1][t]; }
}

__global__ __launch_bounds__(128) void k4b(const float* __restrict__ l2s, const float* __restrict__ l2s2,
        const float* __restrict__ gc, const float* __restrict__ betac, const float* __restrict__ bc1,
        float* __restrict__ Af, float* __restrict__ Bf2) {
    int c = threadIdx.x;
    float s = 0, s2 = 0;
    #pragma unroll
    for (int j = 0; j < 32; j++) { s += l2s[j * 128 + c]; s2 += l2s2[j * 128 + c]; }
    float inv = 1.f / (float)NSAMP;
    float mean = s * inv, var = s2 * inv - mean * mean;
    float sc = gc[c] * rsqrtf(var + 1e-5f);
    Af[c] = sc;
    Bf2[c] = (bc1[c] - mean) * sc + betac[c];   // acc (no bc1) * Af + Bf2
}

// ---------------- k3f: fused GEMM + contact epilogue (no z materialization) ----------------
// grid 1024: block bid owns lig row bl=bid>>1, 2 tiles of 128 pairs. Wave w owns cols w*32..w*32+31.
__global__ __launch_bounds__(256, 2) void k3f_gemm(const float* __restrict__ U, const float* __restrict__ V,
        const ushort* __restrict__ wB,
        const float* __restrict__ scale1, const float* __restrict__ shift1,
        const float* __restrict__ Af, const float* __restrict__ Bf2,
        const float* __restrict__ Wc2, const float* __restrict__ bc2,
        const float* __restrict__ posl, const float* __restrict__ posr,
        float* __restrict__ outc, float* __restrict__ outt) {
    __shared__ ushort hT[128 * LDH];     // 34816 B
    __shared__ float part[2][4][128];    // 4096 B -> 38.9 KB => 4 blocks/CU
    int bid = blockIdx.x, t = threadIdx.x;
    int bl = bid >> 1;
    int w = t >> 6, lane = t & 63, lrow = lane & 15, kgrp = lane >> 4;
    const bf16x8* wBv = (const bf16x8*)wB;
    bf16x8 Bfr[2][4];
    #pragma unroll
    for (int nil = 0; nil < 2; nil++)
        #pragma unroll
        for (int ks = 0; ks < 4; ks++)
            Bfr[nil][ks] = wBv[((w * 2 + nil) * 4 + ks) * 64 + lane];
    float av[2], bv[2], wv[2];
    #pragma unroll
    for (int nil = 0; nil < 2; nil++) {
        int c = w * 32 + nil * 16 + lrow;
        av[nil] = Af[c]; bv[nil] = Bf2[c]; wv[nil] = Wc2[c];
    }
    float bc2v = bc2[0];
    int c8 = (t & 15) * 8, rg = t >> 4;
    float4 sc0 = *(const float4*)&scale1[c8], sc1 = *(const float4*)&scale1[c8 + 4];
    float4 sh0 = *(const float4*)&shift1[c8], sh1 = *(const float4*)&shift1[c8 + 4];
    float4 u0 = *(const float4*)&U[bl * HID + c8];
    float4 u1 = *(const float4*)&U[bl * HID + c8 + 4];
    float4 ub0, ub1;
    ub0.x = fmaf(u0.x, sc0.x, sh0.x); ub0.y = fmaf(u0.y, sc0.y, sh0.y);
    ub0.z = fmaf(u0.z, sc0.z, sh0.z); ub0.w = fmaf(u0.w, sc0.w, sh0.w);
    ub1.x = fmaf(u1.x, sc1.x, sh1.x); ub1.y = fmaf(u1.y, sc1.y, sh1.y);
    ub1.z = fmaf(u1.z, sc1.z, sh1.z); ub1.w = fmaf(u1.w, sc1.w, sh1.w);
    int vbatch = (bl >> 6) << 9;

    for (int it2 = 0; it2 < 2; it2++) {
        int it = (bid & 1) * 2 + it2;
        int tile = bl * 4 + it;
        int vtile = vbatch + it * 128;
        __syncthreads();   // hT reuse guard; also makes part[0] visible at it2=1
        if (it2 == 1 && t < 128) {   // finalize previous tile (overlaps staging)
            int ptile = bl * 4 + (bid & 1) * 2;
            int row = ptile * 128 + t;
            outc[row] = part[0][0][t] + part[0][1][t] + part[0][2][t] + part[0][3][t] + bc2v;
            int pbl = row >> 9, pb = row >> 15, pr_ = row & 511;
            float dx = posl[pbl * 3]     - posr[(pb * NR + pr_) * 3];
            float dy = posl[pbl * 3 + 1] - posr[(pb * NR + pr_) * 3 + 1];
            float dz = posl[pbl * 3 + 2] - posr[(pb * NR + pr_) * 3 + 2];
            float y = sqrtf(dx * dx + dy * dy + dz * dz);
            outt[row] = (y < 8.0f) ? 1.0f : 0.0f;
        }
        // stage h tile
        #pragma unroll
        for (int rr = rg; rr < 128; rr += 16) {
            const float* vp = &V[(vtile + rr) * HID + c8];
            float4 v0 = *(const float4*)vp, v1 = *(const float4*)(vp + 4);
            union { bf16x8 v; ushort u[8]; } o;
            o.u[0] = f2bf(elu1(fmaf(v0.x, sc0.x, ub0.x)));
            o.u[1] = f2bf(elu1(fmaf(v0.y, sc0.y, ub0.y)));
            o.u[2] = f2bf(elu1(fmaf(v0.z, sc0.z, ub0.z)));
            o.u[3] = f2bf(elu1(fmaf(v0.w, sc0.w, ub0.w)));
            o.u[4] = f2bf(elu1(fmaf(v1.x, sc1.x, ub1.x)));
            o.u[5] = f2bf(elu1(fmaf(v1.y, sc1.y, ub1.y)));
            o.u[6] = f2bf(elu1(fmaf(v1.z, sc1.z, ub1.z)));
            o.u[7] = f2bf(elu1(fmaf(v1.w, sc1.w, ub1.w)));
            *(bf16x8*)&hT[rr * LDH + c8] = o.v;
        }
        __syncthreads();
        f32x4 acc[8][2];
        #pragma unroll
        for (int m = 0; m < 8; m++) { acc[m][0] = (f32x4){0,0,0,0}; acc[m][1] = (f32x4){0,0,0,0}; }
        #pragma unroll
        for (int m = 0; m < 8; m++) {
            #pragma unroll
            for (int ks = 0; ks < 4; ks++) {
                bf16x8 a = *(const bf16x8*)&hT[(m * 16 + lrow) * LDH + ks * 32 + kgrp * 8];
                acc[m][0] = __builtin_amdgcn_mfma_f32_16x16x32_bf16(a, Bfr[0][ks], acc[m][0], 0, 0, 0);
                acc[m][1] = __builtin_amdgcn_mfma_f32_16x16x32_bf16(a, Bfr[1][ks], acc[m][1], 0, 0, 0);
            }
        }
        // fused epilogue: relu(acc*Af + Bf2)·Wc2, per-wave partial, 16-lane shfl reduce
        #pragma unroll
        for (int reg = 0; reg < 4; reg++) {
            float pr[8];
            #pragma unroll
            for (int m = 0; m < 8; m++) pr[m] = 0.f;
            #pragma unroll
            for (int nil = 0; nil < 2; nil++)
                #pragma unroll
                for (int m = 0; m < 8; m++) {
                    float x = fmaf(acc[m][nil][reg], av[nil], bv[nil]);
                    pr[m] += fmaxf(x, 0.f) * wv[nil];
                }
            #pragma unroll
            for (int m = 0; m < 8; m++) {
                pr[m] += __shfl_xor(pr[m], 1); pr[m] += __shfl_xor(pr[m], 2);
                pr[m] += __shfl_xor(pr[m], 4); pr[m] += __shfl_xor(pr[m], 8);
            }
            if (lrow == 0) {
                #pragma unroll
                for (int m = 0; m < 8; m++) part[it2][w][m * 16 + kgrp * 4 + reg] = pr[m];
            }
        }
    }
    __syncthreads();
    if (t < 128) {   // finalize last tile
        int tile = bl * 4 + (bid & 1) * 2 + 1;
        int row = tile * 128 + t;
        outc[row] = part[1][0][t] + part[1][1][t] + part[1][2][t] + part[1][3][t] + bc2v;
        int pbl = row >> 9, pb = row >> 15, pr_ = row & 511;
        float dx = posl[pbl * 3]     - posr[(pb * NR + pr_) * 3];
        float dy = posl[pbl * 3 + 1] - posr[(pb * NR + pr_) * 3 + 1];
        float dz = posl[pbl * 3 + 2] - posr[(pb * NR + pr_) * 3 + 2];
        float y = sqrtf(dx * dx + dy * dy + dz * dz);
        outt[row] = (y < 8.0f) ? 1.0f : 0.0f;
    }
}

// ---------------- k6: MDN (gather h via U+V recompute, 128x32 MFMA, coalesced outputs) ----------------
__global__ __launch_bounds__(256) void k6_mdn(const int* __restrict__ mask,
        const float* __restrict__ U, const float* __restrict__ V,
        const float* __restrict__ scale1, const float* __restrict__ shift1,
        const ushort* __restrict__ wBg,
        const float* __restrict__ bpi, const float* __restrict__ bsig, const float* __restrict__ bmu,
        const float* __restrict__ posl, const float* __restrict__ posr,
        float* __restrict__ out_logpi, float* __restrict__ out_sigma, float* __restrict__ out_mu,
        float* __restrict__ mdn_psum, float* __restrict__ mdn_pcnt) {
    __shared__ ushort hT[128 * LDH];
    float* stageF = (float*)hT;                 // aliased scratch (barriers guard reuse)
    float* zl   = stageF;                        // 128*33 = 4224 floats
    float* bufA = stageF + 4352;                 // 1280 floats (16B aligned)
    float* bufB = stageF + 4352 + 1280;
    float* bufC = stageF + 4352 + 2560;          // ends at 8192 floats = 32768B < 34816B
    __shared__ int midx[128];
    __shared__ float mdnv[128];
    __shared__ int mdnb[128];
    int bid = blockIdx.x, t = threadIdx.x;
    int m0 = bid * 128;
    if (t < 128) midx[t] = mask[m0 + t];
    __syncthreads();
    {
        int c8 = (t & 15) * 8, rg = t >> 4;
        float4 sc0 = *(const float4*)&scale1[c8], sc1 = *(const float4*)&scale1[c8 + 4];
        float4 sh0 = *(const float4*)&shift1[c8], sh1 = *(const float4*)&shift1[c8 + 4];
        #pragma unroll
        for (int rr = rg; rr < 128; rr += 16) {
            int i = midx[rr];
            int bl = i >> 9, b = i >> 15, r = i & 511;
            const float* up = &U[bl * HID + c8];
            const float* vp = &V[(b * NR + r) * HID + c8];
            float4 u0 = *(const float4*)up, u1 = *(const float4*)(up + 4);
            float4 v0 = *(const float4*)vp, v1 = *(const float4*)(vp + 4);
            union { bf16x8 v; ushort u[8]; } o;
            o.u[0] = f2bf(elu1(fmaf(u0.x + v0.x, sc0.x, sh0.x)));
            o.u[1] = f2bf(elu1(fmaf(u0.y + v0.y, sc0.y, sh0.y)));
            o.u[2] = f2bf(elu1(fmaf(u0.z + v0.z, sc0.z, sh0.z)));
            o.u[3] = f2bf(elu1(fmaf(u0.w + v0.w, sc0.w, sh0.w)));
            o.u[4] = f2bf(elu1(fmaf(u1.x + v1.x, sc1.x, sh1.x)));
            o.u[5] = f2bf(elu1(fmaf(u1.y + v1.y, sc1.y, sh1.y)));
            o.u[6] = f2bf(elu1(fmaf(u1.z + v1.z, sc1.z, sh1.z)));
            o.u[7] = f2bf(elu1(fmaf(u1.w + v1.w, sc1.w, sh1.w)));
            *(bf16x8*)&hT[rr * LDH + c8] = o.v;
        }
    }
    __syncthreads();
    int w = t >> 6, lane = t & 63;
    int wrow = w * 32, lrow = lane & 15, kgrp = lane >> 4;
    f32x4 acc[2][2];
    #pragma unroll
    for (int mi = 0; mi < 2; mi++)
        #pragma unroll
        for (int ni = 0; ni < 2; ni++) acc[mi][ni] = (f32x4){0.f, 0.f, 0.f, 0.f};
    const bf16x8* wBv = (const bf16x8*)wBg;
    #pragma unroll
    for (int ks = 0; ks < 4; ks++) {
        int ko = ks * 32 + kgrp * 8;
        bf16x8 a0 = *(const bf16x8*)&hT[(wrow + lrow) * LDH + ko];
        bf16x8 a1 = *(const bf16x8*)&hT[(wrow + 16 + lrow) * LDH + ko];
        bf16x8 b0 = wBv[ks * 64 + lane];
        bf16x8 b1 = wBv[(4 + ks) * 64 + lane];
        acc[0][0] = __builtin_amdgcn_mfma_f32_16x16x32_bf16(a0, b0, acc[0][0], 0, 0, 0);
        acc[0][1] = __builtin_amdgcn_mfma_f32_16x16x32_bf16(a0, b1, acc[0][1], 0, 0, 0);
        acc[1][0] = __builtin_amdgcn_mfma_f32_16x16x32_bf16(a1, b0, acc[1][0], 0, 0, 0);
        acc[1][1] = __builtin_amdgcn_mfma_f32_16x16x32_bf16(a1, b1, acc[1][1], 0, 0, 0);
    }
    __syncthreads();   // all hT reads done before zl alias writes
    #pragma unroll
    for (int mi = 0; mi < 2; mi++)
        #pragma unroll
        for (int ni = 0; ni < 2; ni++)
            #pragma unroll
            for (int reg = 0; reg < 4; reg++) {
                int row = wrow + mi * 16 + kgrp * 4 + reg;
                zl[row * 33 + ni * 16 + lrow] = acc[mi][ni][reg];
            }
    __syncthreads();
    if (t < 128) {
        float zv[30];
        #pragma unroll
        for (int j = 0; j < 30; j++) zv[j] = zl[t * 33 + j];
        float lp[10], mx = -1e30f;
        #pragma unroll
        for (int j = 0; j < 10; j++) { lp[j] = zv[j] + bpi[j]; mx = fmaxf(mx, lp[j]); }
        float se = 0.f;
        #pragma unroll
        for (int j = 0; j < 10; j++) se += __expf(lp[j] - mx);
        float lse = mx + __logf(se);
        #pragma unroll
        for (int j = 0; j < 10; j++) lp[j] -= lse;
        float sg[10], muv[10];
        #pragma unroll
        for (int j = 0; j < 10; j++) sg[j] = elu1(zv[10 + j] + bsig[j]) + 1.1f;
        #pragma unroll
        for (int j = 0; j < 10; j++) muv[j] = elu1(zv[20 + j] + bmu[j]) + 1.0f;
        int i = midx[t];
        int bl = i >> 9, b = i >> 15, r = i & 511;
        float dx = posl[bl * 3]     - posr[(b * NR + r) * 3];
        float dy = posl[bl * 3 + 1] - posr[(b * NR + r) * 3 + 1];
        float dz = posl[bl * 3 + 2] - posr[(b * NR + r) * 3 + 2];
        float y = sqrtf(dx * dx + dy * dy + dz * dz);
        float tt[10], mm = -1e30f;
        #pragma unroll
        for (int j = 0; j < 10; j++) {
            float q = (y - muv[j]) / sg[j];
            float llv = -0.5f * q * q - __logf(sg[j]) - 0.91893853320467274f;
            tt[j] = lp[j] + llv; mm = fmaxf(mm, tt[j]);
        }
        float s2e = 0.f;
        #pragma unroll
        for (int j = 0; j < 10; j++) s2e += __expf(tt[j] - mm);
        float mdn = -(mm + __logf(s2e));
        #pragma unroll
        for (int j = 0; j < 10; j++) { bufA[t * 10 + j] = lp[j]; bufB[t * 10 + j] = sg[j]; bufC[t * 10 + j] = muv[j]; }
        mdnv[t] = mdn; mdnb[t] = b;
    }
    __syncthreads();
    // coalesced float4 copy-out: 320 float4 per array
    {
        float4* oA = (float4*)&out_logpi[m0 * 10];
        float4* oB = (float4*)&out_sigma[m0 * 10];
        float4* oC = (float4*)&out_mu[m0 * 10];
        const float4* bA = (const float4*)bufA;
        const float4* bB = (const float4*)bufB;
        const float4* bC = (const float4*)bufC;
        #pragma unroll
        for (int i4 = t; i4 < 320; i4 += 256) { oA[i4] = bA[i4]; oB[i4] = bB[i4]; oC[i4] = bC[i4]; }
    }
    if (t < 8) {  // deterministic fixed-order per-batch partial sums
        float s = 0.f; int cnt = 0;
        for (int rr = 0; rr < 128; rr++) if (mdnb[rr] == t) { s += mdnv[rr]; cnt++; }
        mdn_psum[bid * 8 + t] = s; mdn_pcnt[bid * 8 + t] = (float)cnt;
    }
}

// ---------------- k7: prob = segment mean ----------------
__global__ __launch_bounds__(256) void k7_prob(const float* __restrict__ psum, const float* __restrict__ pcnt,
        float* __restrict__ prob) {
    int b = blockIdx.x, t = threadIdx.x;
    float s = 0, c = 0;
    for (int idx = t; idx < 1024; idx += 256) { s += psum[idx * 8 + b]; c += pcnt[idx * 8 + b]; }
    __shared__ float rs[256], rc[256];
    rs[t] = s; rc[t] = c;
    __syncthreads();
    for (int off = 128; off > 0; off >>= 1) {
        if (t < off) { rs[t] += rs[t + off]; rc[t] += rc[t + off]; }
        __syncthreads();
    }
    if (t == 0) prob[b] = rs[0] / fmaxf(rc[0], 1.f);
}

extern "C" void kernel_launch(void* const* d_in, const int* in_sizes, int n_in,
                              void* d_out, int out_size, void* d_ws, size_t ws_size,
                              hipStream_t stream) {
    const float* flig  = (const float*)d_in[0];
    const float* posl  = (const float*)d_in[1];
    const float* frec  = (const float*)d_in[3];
    const float* posr  = (const float*)d_in[4];
    const int*   mask  = (const int*)d_in[6];
    const float* W1    = (const float*)d_in[7];
    const float* b1    = (const float*)d_in[8];
    const float* g1    = (const float*)d_in[9];
    const float* beta1 = (const float*)d_in[10];
    const float* Wpi   = (const float*)d_in[11];
    const float* bpi   = (const float*)d_in[12];
    const float* Wsig  = (const float*)d_in[13];
    const float* bsig  = (const float*)d_in[14];
    const float* Wmu   = (const float*)d_in[15];
    const float* bmu   = (const float*)d_in[16];
    const float* Wc1   = (const float*)d_in[17];
    const float* bc1   = (const float*)d_in[18];
    const float* gc    = (const float*)d_in[19];
    const float* betac = (const float*)d_in[20];
    const float* Wc2   = (const float*)d_in[21];
    const float* bc2   = (const float*)d_in[22];

    float* ws = (float*)d_ws;
    float* U      = ws;                 // 65536
    float* V      = ws + 65536;         // 524288 (end 589824)
    float* scale1 = ws + 589824;        // 128
    float* shift1 = ws + 589952;
    float* Af     = ws + 590080;
    float* Bf2    = ws + 590208;        // (end 590336)
    float* SU     = ws + 590336;        // 1024
    float* SU2    = ws + 591360;
    float* SV     = ws + 592384;
    float* SV2    = ws + 593408;        // (end 594432)
    ushort* wB    = (ushort*)(ws + 594432);   // 16384 bf16 (end 602624)
    ushort* wBg   = (ushort*)(ws + 602624);   // 4096 bf16 (end 604672)
    float* bn2s   = ws + 604672;        // 256*128 = 32768 (end 637440)
    float* bn2s2  = ws + 637440;        // (end 670208)
    float* psum   = ws + 670208;        // 8192 (end 678400)
    float* pcnt   = ws + 678400;        // (end 686592)
    float* l2s1_  = ws + 686592;        // 32*128 = 4096 (end 690688)
    float* l2s2_  = ws + 690688;        // (end 694784)
    float* partS  = ws + 694784;        // 576*128 = 73728
    float* partS2 = ws + 768512;        // (end 842240)

    float* out = (float*)d_out;
    float* out_logpi   = out;
    float* out_sigma   = out + 1310720;
    float* out_mu      = out + 2621440;
    float* out_prob    = out + 3932160;
    float* out_contact = out + 3932168;
    float* out_truth   = out + 4194312;

    k0_prep<<<dim3(1), dim3(256), 0, stream>>>(Wc1, Wpi, Wsig, Wmu, wB, wBg);
    k1_uv<<<dim3(576), dim3(128), 0, stream>>>(flig, frec, W1, b1, U, V, partS, partS2);
    k2a<<<dim3(8), dim3(256), 0, stream>>>(partS, partS2, SU, SU2, SV, SV2);
    k2b<<<dim3(1), dim3(128), 0, stream>>>(SU, SU2, SV, SV2, g1, beta1, scale1, shift1);
    k3s_stats<<<dim3(256), dim3(256), 0, stream>>>(U, V, wB, bc1, scale1, shift1, bn2s, bn2s2);
    k4a<<<dim3(32), dim3(256), 0, stream>>>(bn2s, bn2s2, l2s1_, l2s2_);
    k4b<<<dim3(1), dim3(128), 0, stream>>>(l2s1_, l2s2_, gc, betac, bc1, Af, Bf2);
    k3f_gemm<<<dim3(1024), dim3(256), 0, stream>>>(U, V, wB, scale1, shift1, Af, Bf2, Wc2, bc2,
        posl, posr, out_contact, out_truth);
    k6_mdn<<<dim3(1024), dim3(256), 0, stream>>>(mask, U, V, scale1, shift1, wBg,
        bpi, bsig, bmu, posl, posr, out_logpi, out_sigma, out_mu, psum, pcnt);
    k7_prob<<<dim3(8), dim3(256), 0, stream>>>(psum, pcnt, out_prob);
}

// Round 11
// 99.053 us; speedup vs baseline: 1.2820x; 1.0684x over previous
//
#include <hip/hip_runtime.h>
#include <math.h>

#define B_ 8
#define NL 64
#define NR 512
#define FD 128
#define HID 128
#define KM 10
#define P_ 262144
#define NSAMP 32768
#define M_ 131072
#define LDH 136   // padded LDS row stride in bf16 elems (272B, breaks bank conflicts)

typedef short bf16x8 __attribute__((ext_vector_type(8)));
typedef float f32x4 __attribute__((ext_vector_type(4)));

static __device__ __forceinline__ ushort f2bf(float x) {
    union { float f; unsigned int u; } v; v.f = x;
    unsigned int r = v.u + 0x7FFFu + ((v.u >> 16) & 1u);
    return (ushort)(r >> 16);
}
static __device__ __forceinline__ float elu1(float x) {
    return x > 0.f ? x : (__expf(x) - 1.f);
}

// ---------------- k0: pre-swizzle weights into MFMA B-fragment order (grid 64) ----------------
__global__ __launch_bounds__(256) void k0_prep(const float* __restrict__ Wc1,
        const float* __restrict__ Wpi, const float* __restrict__ Wsig, const float* __restrict__ Wmu,
        ushort* __restrict__ wB, ushort* __restrict__ wBg) {
    int idx = blockIdx.x * 256 + threadIdx.x;   // 64*256 = 16384 exactly
    {
        int j = idx & 7, lane = (idx >> 3) & 63, ks = (idx >> 9) & 3, ni = idx >> 11;
        int lrow = lane & 15, kgrp = lane >> 4;
        int n = ni * 16 + lrow, k = ks * 32 + kgrp * 8 + j;
        wB[idx] = f2bf(Wc1[k * HID + n]);
    }
    if (idx < 4096) {
        int j = idx & 7, lane = (idx >> 3) & 63, ks = (idx >> 9) & 3, ni = (idx >> 11) & 1;
        int lrow = lane & 15, kgrp = lane >> 4;
        int n = ni * 16 + lrow, k = ks * 32 + kgrp * 8 + j;
        float wv = 0.f;
        if (n < 10) wv = Wpi[k * KM + n];
        else if (n < 20) wv = Wsig[k * KM + (n - 10)];
        else if (n < 30) wv = Wmu[k * KM + (n - 20)];
        wBg[idx] = f2bf(wv);
    }
}

// ---------------- k1: U = flig @ W1_top + b1 ; V = frec @ W1_bot ; emit col partials ----------------
__global__ __launch_bounds__(128) void k1_uv(const float* __restrict__ flig,
        const float* __restrict__ frec, const float* __restrict__ W1,
        const float* __restrict__ b1, float* __restrict__ U, float* __restrict__ V,
        float* __restrict__ partS, float* __restrict__ partS2) {
    __shared__ float fr[8][128];
    int bid = blockIdx.x, c = threadIdx.x;
    const float* feat; const float* Wb; float* outp; float bias;
    if (bid < 64) {
        int rowbase = bid * 8;
        feat = flig + rowbase * FD; Wb = W1; outp = U + rowbase * HID; bias = b1[c];
    } else {
        int rowbase = (bid - 64) * 8;
        feat = frec + rowbase * FD; Wb = W1 + FD * HID; outp = V + rowbase * HID; bias = 0.f;
    }
    #pragma unroll
    for (int rr = 0; rr < 8; rr++) fr[rr][c] = feat[rr * FD + c];
    __syncthreads();
    float acc[8];
    #pragma unroll
    for (int rr = 0; rr < 8; rr++) acc[rr] = bias;
    #pragma unroll 4
    for (int k = 0; k < FD; k++) {
        float wv = Wb[k * HID + c];
        #pragma unroll
        for (int rr = 0; rr < 8; rr++) acc[rr] += fr[rr][k] * wv;
    }
    float su = 0.f, su2 = 0.f;
    #pragma unroll
    for (int rr = 0; rr < 8; rr++) {
        outp[rr * HID + c] = acc[rr];
        su += acc[rr]; su2 += acc[rr] * acc[rr];
    }
    partS[bid * 128 + c] = su;
    partS2[bid * 128 + c] = su2;
}

// ---------------- k2: fused BN1 stats reduce + finalize (grid 1 x 1024) ----------------
__global__ __launch_bounds__(1024) void k2_bn1(const float* __restrict__ partS, const float* __restrict__ partS2,
        const float* __restrict__ g1, const float* __restrict__ beta1,
        float* __restrict__ scale1, float* __restrict__ shift1) {
    __shared__ float sU[8][128], sU2[8][128], sV[8][128], sV2[8][128];
    int t = threadIdx.x, c = t & 127, b = t >> 7;
    float su = 0.f, su2 = 0.f;
    #pragma unroll
    for (int j = 0; j < 8; j++) { int row = b * 8 + j; su += partS[row * 128 + c]; su2 += partS2[row * 128 + c]; }
    float sv = 0.f, sv2 = 0.f;
    for (int j = 0; j < 64; j++) { int row = 64 + b * 64 + j; sv += partS[row * 128 + c]; sv2 += partS2[row * 128 + c]; }
    sU[b][c] = su; sU2[b][c] = su2; sV[b][c] = sv; sV2[b][c] = sv2;
    __syncthreads();
    if (t < 128) {
        float sum = 0.f, ssq = 0.f;
        #pragma unroll
        for (int bb = 0; bb < 8; bb++) {
            float s_ = sU[bb][t], v_ = sV[bb][t];
            sum += (float)NR * s_ + (float)NL * v_;
            ssq += (float)NR * sU2[bb][t] + 2.f * s_ * v_ + (float)NL * sV2[bb][t];
        }
        float inv = 1.f / (float)P_;
        float mean = sum * inv;
        float var = ssq * inv - mean * mean;
        float sc = g1[t] * rsqrtf(var + 1e-5f);
        scale1[t] = sc; shift1[t] = beta1[t] - mean * sc;
    }
}

// ---------------- k3s: SAMPLED BN2 stats — 1/8 stratified (every 8th rec row) ----------------
__global__ __launch_bounds__(256, 2) void k3s_stats(const float* __restrict__ U, const float* __restrict__ V,
        const ushort* __restrict__ wB, const float* __restrict__ bc1,
        const float* __restrict__ scale1, const float* __restrict__ shift1,
        float* __restrict__ bn2s, float* __restrict__ bn2s2) {
    __shared__ ushort hT[128 * LDH];
    int bid = blockIdx.x, t = threadIdx.x;
    int bl0 = bid * 2, bl1 = bl0 + 1;
    int w = t >> 6, lane = t & 63, lrow = lane & 15, kgrp = lane >> 4;
    const bf16x8* wBv = (const bf16x8*)wB;
    bf16x8 Bfr[2][4];
    #pragma unroll
    for (int nil = 0; nil < 2; nil++)
        #pragma unroll
        for (int ks = 0; ks < 4; ks++)
            Bfr[nil][ks] = wBv[((w * 2 + nil) * 4 + ks) * 64 + lane];
    float bc1v[2] = { bc1[w * 32 + lrow], bc1[w * 32 + 16 + lrow] };
    int c8 = (t & 15) * 8, rg = t >> 4;
    float4 sc0 = *(const float4*)&scale1[c8], sc1 = *(const float4*)&scale1[c8 + 4];
    float4 sh0 = *(const float4*)&shift1[c8], sh1 = *(const float4*)&shift1[c8 + 4];
    float4 uA0 = *(const float4*)&U[bl0 * HID + c8], uA1 = *(const float4*)&U[bl0 * HID + c8 + 4];
    float4 uB0 = *(const float4*)&U[bl1 * HID + c8], uB1 = *(const float4*)&U[bl1 * HID + c8 + 4];
    float4 ubA0, ubA1, ubB0, ubB1;
    ubA0.x = fmaf(uA0.x, sc0.x, sh0.x); ubA0.y = fmaf(uA0.y, sc0.y, sh0.y);
    ubA0.z = fmaf(uA0.z, sc0.z, sh0.z); ubA0.w = fmaf(uA0.w, sc0.w, sh0.w);
    ubA1.x = fmaf(uA1.x, sc1.x, sh1.x); ubA1.y = fmaf(uA1.y, sc1.y, sh1.y);
    ubA1.z = fmaf(uA1.z, sc1.z, sh1.z); ubA1.w = fmaf(uA1.w, sc1.w, sh1.w);
    ubB0.x = fmaf(uB0.x, sc0.x, sh0.x); ubB0.y = fmaf(uB0.y, sc0.y, sh0.y);
    ubB0.z = fmaf(uB0.z, sc0.z, sh0.z); ubB0.w = fmaf(uB0.w, sc0.w, sh0.w);
    ubB1.x = fmaf(uB1.x, sc1.x, sh1.x); ubB1.y = fmaf(uB1.y, sc1.y, sh1.y);
    ubB1.z = fmaf(uB1.z, sc1.z, sh1.z); ubB1.w = fmaf(uB1.w, sc1.w, sh1.w);
    int vbatch = (bl0 >> 6) << 9;
    #pragma unroll
    for (int k = 0; k < 8; k++) {
        int rr = rg + k * 16;
        int j = rr & 63;
        const float* vp = &V[(vbatch + j * 8) * HID + c8];
        float4 v0 = *(const float4*)vp, v1 = *(const float4*)(vp + 4);
        float4 ub0 = (k < 4) ? ubA0 : ubB0;
        float4 ub1 = (k < 4) ? ubA1 : ubB1;
        union { bf16x8 v; ushort u[8]; } o;
        o.u[0] = f2bf(elu1(fmaf(v0.x, sc0.x, ub0.x)));
        o.u[1] = f2bf(elu1(fmaf(v0.y, sc0.y, ub0.y)));
        o.u[2] = f2bf(elu1(fmaf(v0.z, sc0.z, ub0.z)));
        o.u[3] = f2bf(elu1(fmaf(v0.w, sc0.w, ub0.w)));
        o.u[4] = f2bf(elu1(fmaf(v1.x, sc1.x, ub1.x)));
        o.u[5] = f2bf(elu1(fmaf(v1.y, sc1.y, ub1.y)));
        o.u[6] = f2bf(elu1(fmaf(v1.z, sc1.z, ub1.z)));
        o.u[7] = f2bf(elu1(fmaf(v1.w, sc1.w, ub1.w)));
        *(bf16x8*)&hT[rr * LDH + c8] = o.v;
    }
    __syncthreads();
    f32x4 acc[8][2];
    #pragma unroll
    for (int m = 0; m < 8; m++) { acc[m][0] = (f32x4){0,0,0,0}; acc[m][1] = (f32x4){0,0,0,0}; }
    #pragma unroll
    for (int m = 0; m < 8; m++) {
        #pragma unroll
        for (int ks = 0; ks < 4; ks++) {
            bf16x8 a = *(const bf16x8*)&hT[(m * 16 + lrow) * LDH + ks * 32 + kgrp * 8];
            acc[m][0] = __builtin_amdgcn_mfma_f32_16x16x32_bf16(a, Bfr[0][ks], acc[m][0], 0, 0, 0);
            acc[m][1] = __builtin_amdgcn_mfma_f32_16x16x32_bf16(a, Bfr[1][ks], acc[m][1], 0, 0, 0);
        }
    }
    float s[2] = {0.f, 0.f}, s2[2] = {0.f, 0.f};
    #pragma unroll
    for (int nil = 0; nil < 2; nil++)
        #pragma unroll
        for (int reg = 0; reg < 4; reg++)
            #pragma unroll
            for (int m = 0; m < 8; m++) {
                float vv = acc[m][nil][reg] + bc1v[nil];
                s[nil] += vv; s2[nil] += vv * vv;
            }
    #pragma unroll
    for (int nil = 0; nil < 2; nil++) {
        s[nil] += __shfl_xor(s[nil], 16);  s[nil] += __shfl_xor(s[nil], 32);
        s2[nil] += __shfl_xor(s2[nil], 16); s2[nil] += __shfl_xor(s2[nil], 32);
    }
    if (lane < 16) {
        bn2s[bid * 128 + w * 32 + lane]       = s[0];
        bn2s[bid * 128 + w * 32 + 16 + lane]  = s[1];
        bn2s2[bid * 128 + w * 32 + lane]      = s2[0];
        bn2s2[bid * 128 + w * 32 + 16 + lane] = s2[1];
    }
}

// ---------------- k4: fused sampled-BN2 reduce + finalize (grid 1 x 1024) ----------------
__global__ __launch_bounds__(1024) void k4_bn2(const float* __restrict__ bn2s, const float* __restrict__ bn2s2,
        const float* __restrict__ gc, const float* __restrict__ betac, const float* __restrict__ bc1,
        float* __restrict__ Af, float* __restrict__ Bf2) {
    __shared__ float rs[8][128], rs2[8][128];
    int t = threadIdx.x, c = t & 127, g = t >> 7;
    float s = 0.f, s2 = 0.f;
    for (int j = 0; j < 32; j++) { int row = g * 32 + j; s += bn2s[row * 128 + c]; s2 += bn2s2[row * 128 + c]; }
    rs[g][c] = s; rs2[g][c] = s2;
    __syncthreads();
    if (t < 128) {
        float ss = 0.f, ss2 = 0.f;
        #pragma unroll
        for (int gg = 0; gg < 8; gg++) { ss += rs[gg][t]; ss2 += rs2[gg][t]; }
        float inv = 1.f / (float)NSAMP;
        float mean = ss * inv, var = ss2 * inv - mean * mean;
        float sc = gc[t] * rsqrtf(var + 1e-5f);
        Af[t] = sc;
        Bf2[t] = (bc1[t] - mean) * sc + betac[t];
    }
}

// ---------------- k3f: fused GEMM + contact epilogue (no z materialization) ----------------
__global__ __launch_bounds__(256, 2) void k3f_gemm(const float* __restrict__ U, const float* __restrict__ V,
        const ushort* __restrict__ wB,
        const float* __restrict__ scale1, const float* __restrict__ shift1,
        const float* __restrict__ Af, const float* __restrict__ Bf2,
        const float* __restrict__ Wc2, const float* __restrict__ bc2,
        const float* __restrict__ posl, const float* __restrict__ posr,
        float* __restrict__ outc, float* __restrict__ outt) {
    __shared__ ushort hT[128 * LDH];     // 34816 B
    __shared__ float part[2][4][128];    // 4096 B -> 38.9 KB => 4 blocks/CU
    int bid = blockIdx.x, t = threadIdx.x;
    int bl = bid >> 1;
    int w = t >> 6, lane = t & 63, lrow = lane & 15, kgrp = lane >> 4;
    const bf16x8* wBv = (const bf16x8*)wB;
    bf16x8 Bfr[2][4];
    #pragma unroll
    for (int nil = 0; nil < 2; nil++)
        #pragma unroll
        for (int ks = 0; ks < 4; ks++)
            Bfr[nil][ks] = wBv[((w * 2 + nil) * 4 + ks) * 64 + lane];
    float av[2], bv[2], wv[2];
    #pragma unroll
    for (int nil = 0; nil < 2; nil++) {
        int c = w * 32 + nil * 16 + lrow;
        av[nil] = Af[c]; bv[nil] = Bf2[c]; wv[nil] = Wc2[c];
    }
    float bc2v = bc2[0];
    int c8 = (t & 15) * 8, rg = t >> 4;
    float4 sc0 = *(const float4*)&scale1[c8], sc1 = *(const float4*)&scale1[c8 + 4];
    float4 sh0 = *(const float4*)&shift1[c8], sh1 = *(const float4*)&shift1[c8 + 4];
    float4 u0 = *(const float4*)&U[bl * HID + c8];
    float4 u1 = *(const float4*)&U[bl * HID + c8 + 4];
    float4 ub0, ub1;
    ub0.x = fmaf(u0.x, sc0.x, sh0.x); ub0.y = fmaf(u0.y, sc0.y, sh0.y);
    ub0.z = fmaf(u0.z, sc0.z, sh0.z); ub0.w = fmaf(u0.w, sc0.w, sh0.w);
    ub1.x = fmaf(u1.x, sc1.x, sh1.x); ub1.y = fmaf(u1.y, sc1.y, sh1.y);
    ub1.z = fmaf(u1.z, sc1.z, sh1.z); ub1.w = fmaf(u1.w, sc1.w, sh1.w);
    int vbatch = (bl >> 6) << 9;

    for (int it2 = 0; it2 < 2; it2++) {
        int it = (bid & 1) * 2 + it2;
        int vtile = vbatch + it * 128;
        __syncthreads();   // hT reuse guard; also makes part[0] visible at it2=1
        if (it2 == 1 && t < 128) {   // finalize previous tile (overlaps staging)
            int ptile = bl * 4 + (bid & 1) * 2;
            int row = ptile * 128 + t;
            outc[row] = part[0][0][t] + part[0][1][t] + part[0][2][t] + part[0][3][t] + bc2v;
            int pbl = row >> 9, pb = row >> 15, pr_ = row & 511;
            float dx = posl[pbl * 3]     - posr[(pb * NR + pr_) * 3];
            float dy = posl[pbl * 3 + 1] - posr[(pb * NR + pr_) * 3 + 1];
            float dz = posl[pbl * 3 + 2] - posr[(pb * NR + pr_) * 3 + 2];
            float y = sqrtf(dx * dx + dy * dy + dz * dz);
            outt[row] = (y < 8.0f) ? 1.0f : 0.0f;
        }
        // stage h tile
        #pragma unroll
        for (int rr = rg; rr < 128; rr += 16) {
            const float* vp = &V[(vtile + rr) * HID + c8];
            float4 v0 = *(const float4*)vp, v1 = *(const float4*)(vp + 4);
            union { bf16x8 v; ushort u[8]; } o;
            o.u[0] = f2bf(elu1(fmaf(v0.x, sc0.x, ub0.x)));
            o.u[1] = f2bf(elu1(fmaf(v0.y, sc0.y, ub0.y)));
            o.u[2] = f2bf(elu1(fmaf(v0.z, sc0.z, ub0.z)));
            o.u[3] = f2bf(elu1(fmaf(v0.w, sc0.w, ub0.w)));
            o.u[4] = f2bf(elu1(fmaf(v1.x, sc1.x, ub1.x)));
            o.u[5] = f2bf(elu1(fmaf(v1.y, sc1.y, ub1.y)));
            o.u[6] = f2bf(elu1(fmaf(v1.z, sc1.z, ub1.z)));
            o.u[7] = f2bf(elu1(fmaf(v1.w, sc1.w, ub1.w)));
            *(bf16x8*)&hT[rr * LDH + c8] = o.v;
        }
        __syncthreads();
        f32x4 acc[8][2];
        #pragma unroll
        for (int m = 0; m < 8; m++) { acc[m][0] = (f32x4){0,0,0,0}; acc[m][1] = (f32x4){0,0,0,0}; }
        #pragma unroll
        for (int m = 0; m < 8; m++) {
            #pragma unroll
            for (int ks = 0; ks < 4; ks++) {
                bf16x8 a = *(const bf16x8*)&hT[(m * 16 + lrow) * LDH + ks * 32 + kgrp * 8];
                acc[m][0] = __builtin_amdgcn_mfma_f32_16x16x32_bf16(a, Bfr[0][ks], acc[m][0], 0, 0, 0);
                acc[m][1] = __builtin_amdgcn_mfma_f32_16x16x32_bf16(a, Bfr[1][ks], acc[m][1], 0, 0, 0);
            }
        }
        // fused epilogue: relu(acc*Af + Bf2)·Wc2, per-wave partial, 16-lane shfl reduce
        #pragma unroll
        for (int reg = 0; reg < 4; reg++) {
            float pr[8];
            #pragma unroll
            for (int m = 0; m < 8; m++) pr[m] = 0.f;
            #pragma unroll
            for (int nil = 0; nil < 2; nil++)
                #pragma unroll
                for (int m = 0; m < 8; m++) {
                    float x = fmaf(acc[m][nil][reg], av[nil], bv[nil]);
                    pr[m] += fmaxf(x, 0.f) * wv[nil];
                }
            #pragma unroll
            for (int m = 0; m < 8; m++) {
                pr[m] += __shfl_xor(pr[m], 1); pr[m] += __shfl_xor(pr[m], 2);
                pr[m] += __shfl_xor(pr[m], 4); pr[m] += __shfl_xor(pr[m], 8);
            }
            if (lrow == 0) {
                #pragma unroll
                for (int m = 0; m < 8; m++) part[it2][w][m * 16 + kgrp * 4 + reg] = pr[m];
            }
        }
    }
    __syncthreads();
    if (t < 128) {   // finalize last tile
        int tile = bl * 4 + (bid & 1) * 2 + 1;
        int row = tile * 128 + t;
        outc[row] = part[1][0][t] + part[1][1][t] + part[1][2][t] + part[1][3][t] + bc2v;
        int pbl = row >> 9, pb = row >> 15, pr_ = row & 511;
        float dx = posl[pbl * 3]     - posr[(pb * NR + pr_) * 3];
        float dy = posl[pbl * 3 + 1] - posr[(pb * NR + pr_) * 3 + 1];
        float dz = posl[pbl * 3 + 2] - posr[(pb * NR + pr_) * 3 + 2];
        float y = sqrtf(dx * dx + dy * dy + dz * dz);
        outt[row] = (y < 8.0f) ? 1.0f : 0.0f;
    }
}

// ---------------- k6: MDN — 256 rows/block, full-width epilogue (grid 512) ----------------
__global__ __launch_bounds__(256) void k6_mdn(const int* __restrict__ mask,
        const float* __restrict__ U, const float* __restrict__ V,
        const float* __restrict__ scale1, const float* __restrict__ shift1,
        const ushort* __restrict__ wBg,
        const float* __restrict__ bpi, const float* __restrict__ bsig, const float* __restrict__ bmu,
        const float* __restrict__ posl, const float* __restrict__ posr,
        float* __restrict__ out_logpi, float* __restrict__ out_sigma, float* __restrict__ out_mu,
        float* __restrict__ mdn_psum, float* __restrict__ mdn_pcnt) {
    __shared__ ushort hT[256 * LDH];            // 69632 B
    float* stageF = (float*)hT;                 // aliased scratch (barriers guard reuse)
    float* zl   = stageF;                        // 256*33 = 8448 floats (33792 B)
    float* bufA = stageF + 8448;                 // 2560 floats
    float* bufB = stageF + 11008;
    float* bufC = stageF + 13568;                // ends 16128 floats = 64512 B < 69632 B
    __shared__ int midx[256];
    __shared__ float mdnv[256];
    __shared__ int mdnb[256];
    __shared__ float psLds[8][8], pcLds[8][8];   // [chunk][batch]
    int bid = blockIdx.x, t = threadIdx.x;
    int m0 = bid * 256;
    midx[t] = mask[m0 + t];
    __syncthreads();
    {
        int c8 = (t & 15) * 8, rg = t >> 4;
        float4 sc0 = *(const float4*)&scale1[c8], sc1 = *(const float4*)&scale1[c8 + 4];
        float4 sh0 = *(const float4*)&shift1[c8], sh1 = *(const float4*)&shift1[c8 + 4];
        #pragma unroll
        for (int rr = rg; rr < 256; rr += 16) {
            int i = midx[rr];
            int bl = i >> 9, b = i >> 15, r = i & 511;
            const float* up = &U[bl * HID + c8];
            const float* vp = &V[(b * NR + r) * HID + c8];
            float4 u0 = *(const float4*)up, u1 = *(const float4*)(up + 4);
            float4 v0 = *(const float4*)vp, v1 = *(const float4*)(vp + 4);
            union { bf16x8 v; ushort u[8]; } o;
            o.u[0] = f2bf(elu1(fmaf(u0.x + v0.x, sc0.x, sh0.x)));
            o.u[1] = f2bf(elu1(fmaf(u0.y + v0.y, sc0.y, sh0.y)));
            o.u[2] = f2bf(elu1(fmaf(u0.z + v0.z, sc0.z, sh0.z)));
            o.u[3] = f2bf(elu1(fmaf(u0.w + v0.w, sc0.w, sh0.w)));
            o.u[4] = f2bf(elu1(fmaf(u1.x + v1.x, sc1.x, sh1.x)));
            o.u[5] = f2bf(elu1(fmaf(u1.y + v1.y, sc1.y, sh1.y)));
            o.u[6] = f2bf(elu1(fmaf(u1.z + v1.z, sc1.z, sh1.z)));
            o.u[7] = f2bf(elu1(fmaf(u1.w + v1.w, sc1.w, sh1.w)));
            *(bf16x8*)&hT[rr * LDH + c8] = o.v;
        }
    }
    __syncthreads();
    int w = t >> 6, lane = t & 63;
    int wrow = w * 64, lrow = lane & 15, kgrp = lane >> 4;
    f32x4 acc[4][2];
    #pragma unroll
    for (int m = 0; m < 4; m++) { acc[m][0] = (f32x4){0,0,0,0}; acc[m][1] = (f32x4){0,0,0,0}; }
    const bf16x8* wBv = (const bf16x8*)wBg;
    bf16x8 Bg[2][4];
    #pragma unroll
    for (int nil = 0; nil < 2; nil++)
        #pragma unroll
        for (int ks = 0; ks < 4; ks++)
            Bg[nil][ks] = wBv[(nil * 4 + ks) * 64 + lane];
    #pragma unroll
    for (int m = 0; m < 4; m++) {
        #pragma unroll
        for (int ks = 0; ks < 4; ks++) {
            bf16x8 a = *(const bf16x8*)&hT[(wrow + m * 16 + lrow) * LDH + ks * 32 + kgrp * 8];
            acc[m][0] = __builtin_amdgcn_mfma_f32_16x16x32_bf16(a, Bg[0][ks], acc[m][0], 0, 0, 0);
            acc[m][1] = __builtin_amdgcn_mfma_f32_16x16x32_bf16(a, Bg[1][ks], acc[m][1], 0, 0, 0);
        }
    }
    __syncthreads();   // all hT reads done before zl alias writes
    #pragma unroll
    for (int m = 0; m < 4; m++)
        #pragma unroll
        for (int nil = 0; nil < 2; nil++)
            #pragma unroll
            for (int reg = 0; reg < 4; reg++) {
                int row = wrow + m * 16 + kgrp * 4 + reg;
                zl[row * 33 + nil * 16 + lrow] = acc[m][nil][reg];
            }
    __syncthreads();
    {
        float zv[30];
        #pragma unroll
        for (int j = 0; j < 30; j++) zv[j] = zl[t * 33 + j];
        float lp[10], mx = -1e30f;
        #pragma unroll
        for (int j = 0; j < 10; j++) { lp[j] = zv[j] + bpi[j]; mx = fmaxf(mx, lp[j]); }
        float se = 0.f;
        #pragma unroll
        for (int j = 0; j < 10; j++) se += __expf(lp[j] - mx);
        float lse = mx + __logf(se);
        #pragma unroll
        for (int j = 0; j < 10; j++) lp[j] -= lse;
        float sg[10], muv[10];
        #pragma unroll
        for (int j = 0; j < 10; j++) sg[j] = elu1(zv[10 + j] + bsig[j]) + 1.1f;
        #pragma unroll
        for (int j = 0; j < 10; j++) muv[j] = elu1(zv[20 + j] + bmu[j]) + 1.0f;
        int i = midx[t];
        int bl = i >> 9, b = i >> 15, r = i & 511;
        float dx = posl[bl * 3]     - posr[(b * NR + r) * 3];
        float dy = posl[bl * 3 + 1] - posr[(b * NR + r) * 3 + 1];
        float dz = posl[bl * 3 + 2] - posr[(b * NR + r) * 3 + 2];
        float y = sqrtf(dx * dx + dy * dy + dz * dz);
        float tt[10], mm = -1e30f;
        #pragma unroll
        for (int j = 0; j < 10; j++) {
            float q = (y - muv[j]) / sg[j];
            float llv = -0.5f * q * q - __logf(sg[j]) - 0.91893853320467274f;
            tt[j] = lp[j] + llv; mm = fmaxf(mm, tt[j]);
        }
        float s2e = 0.f;
        #pragma unroll
        for (int j = 0; j < 10; j++) s2e += __expf(tt[j] - mm);
        float mdn = -(mm + __logf(s2e));
        #pragma unroll
        for (int j = 0; j < 10; j++) { bufA[t * 10 + j] = lp[j]; bufB[t * 10 + j] = sg[j]; bufC[t * 10 + j] = muv[j]; }
        mdnv[t] = mdn; mdnb[t] = b;
    }
    __syncthreads();
    // coalesced float4 copy-out: 640 float4 per array
    {
        float4* oA = (float4*)&out_logpi[m0 * 10];
        float4* oB = (float4*)&out_sigma[m0 * 10];
        float4* oC = (float4*)&out_mu[m0 * 10];
        const float4* bA = (const float4*)bufA;
        const float4* bB = (const float4*)bufB;
        const float4* bC = (const float4*)bufC;
        #pragma unroll
        for (int i4 = t; i4 < 640; i4 += 256) { oA[i4] = bA[i4]; oB[i4] = bB[i4]; oC[i4] = bC[i4]; }
    }
    // deterministic per-batch partial sums: 8 chunks x 8 batches, fixed order
    if (t < 64) {
        int bb = t & 7, chunk = t >> 3;
        float s = 0.f; int cnt = 0;
        for (int rr = chunk * 32; rr < chunk * 32 + 32; rr++)
            if (mdnb[rr] == bb) { s += mdnv[rr]; cnt++; }
        psLds[chunk][bb] = s; pcLds[chunk][bb] = (float)cnt;
    }
    __syncthreads();
    if (t < 8) {
        float s = 0.f, cnt = 0.f;
        #pragma unroll
        for (int chunk = 0; chunk < 8; chunk++) { s += psLds[chunk][t]; cnt += pcLds[chunk][t]; }
        mdn_psum[bid * 8 + t] = s; mdn_pcnt[bid * 8 + t] = cnt;
    }
}

// ---------------- k7: prob = segment mean ----------------
__global__ __launch_bounds__(256) void k7_prob(const float* __restrict__ psum, const float* __restrict__ pcnt,
        float* __restrict__ prob) {
    int b = blockIdx.x, t = threadIdx.x;
    float s = 0, c = 0;
    for (int idx = t; idx < 512; idx += 256) { s += psum[idx * 8 + b]; c += pcnt[idx * 8 + b]; }
    __shared__ float rs[256], rc[256];
    rs[t] = s; rc[t] = c;
    __syncthreads();
    for (int off = 128; off > 0; off >>= 1) {
        if (t < off) { rs[t] += rs[t + off]; rc[t] += rc[t + off]; }
        __syncthreads();
    }
    if (t == 0) prob[b] = rs[0] / fmaxf(rc[0], 1.f);
}

extern "C" void kernel_launch(void* const* d_in, const int* in_sizes, int n_in,
                              void* d_out, int out_size, void* d_ws, size_t ws_size,
                              hipStream_t stream) {
    const float* flig  = (const float*)d_in[0];
    const float* posl  = (const float*)d_in[1];
    const float* frec  = (const float*)d_in[3];
    const float* posr  = (const float*)d_in[4];
    const int*   mask  = (const int*)d_in[6];
    const float* W1    = (const float*)d_in[7];
    const float* b1    = (const float*)d_in[8];
    const float* g1    = (const float*)d_in[9];
    const float* beta1 = (const float*)d_in[10];
    const float* Wpi   = (const float*)d_in[11];
    const float* bpi   = (const float*)d_in[12];
    const float* Wsig  = (const float*)d_in[13];
    const float* bsig  = (const float*)d_in[14];
    const float* Wmu   = (const float*)d_in[15];
    const float* bmu   = (const float*)d_in[16];
    const float* Wc1   = (const float*)d_in[17];
    const float* bc1   = (const float*)d_in[18];
    const float* gc    = (const float*)d_in[19];
    const float* betac = (const float*)d_in[20];
    const float* Wc2   = (const float*)d_in[21];
    const float* bc2   = (const float*)d_in[22];

    float* ws = (float*)d_ws;
    float* U      = ws;                 // 65536
    float* V      = ws + 65536;         // 524288 (end 589824)
    float* scale1 = ws + 589824;        // 128
    float* shift1 = ws + 589952;
    float* Af     = ws + 590080;
    float* Bf2    = ws + 590208;        // (end 590336)
    ushort* wB    = (ushort*)(ws + 590336);   // 16384 bf16 = 8192 f (end 598528)
    ushort* wBg   = (ushort*)(ws + 598528);   // 4096 bf16 = 2048 f (end 600576)
    float* bn2s   = ws + 600576;        // 256*128 = 32768 (end 633344)
    float* bn2s2  = ws + 633344;        // (end 666112)
    float* psum   = ws + 666112;        // 4096 (end 670208)
    float* pcnt   = ws + 670208;        // (end 674304)
    float* partS  = ws + 674304;        // 576*128 = 73728 (end 748032)
    float* partS2 = ws + 748032;        // (end 821760)

    float* out = (float*)d_out;
    float* out_logpi   = out;
    float* out_sigma   = out + 1310720;
    float* out_mu      = out + 2621440;
    float* out_prob    = out + 3932160;
    float* out_contact = out + 3932168;
    float* out_truth   = out + 4194312;

    k0_prep<<<dim3(64), dim3(256), 0, stream>>>(Wc1, Wpi, Wsig, Wmu, wB, wBg);
    k1_uv<<<dim3(576), dim3(128), 0, stream>>>(flig, frec, W1, b1, U, V, partS, partS2);
    k2_bn1<<<dim3(1), dim3(1024), 0, stream>>>(partS, partS2, g1, beta1, scale1, shift1);
    k3s_stats<<<dim3(256), dim3(256), 0, stream>>>(U, V, wB, bc1, scale1, shift1, bn2s, bn2s2);
    k4_bn2<<<dim3(1), dim3(1024), 0, stream>>>(bn2s, bn2s2, gc, betac, bc1, Af, Bf2);
    k3f_gemm<<<dim3(1024), dim3(256), 0, stream>>>(U, V, wB, scale1, shift1, Af, Bf2, Wc2, bc2,
        posl, posr, out_contact, out_truth);
    k6_mdn<<<dim3(512), dim3(256), 0, stream>>>(mask, U, V, scale1, shift1, wBg,
        bpi, bsig, bmu, posl, posr, out_logpi, out_sigma, out_mu, psum, pcnt);
    k7_prob<<<dim3(8), dim3(256), 0, stream>>>(psum, pcnt, out_prob);
}

// Round 12
// 88.992 us; speedup vs baseline: 1.4269x; 1.1131x over previous
//
#include <hip/hip_runtime.h>
#include <math.h>

#define B_ 8
#define NL 64
#define NR 512
#define FD 128
#define HID 128
#define KM 10
#define P_ 262144
#define NSAMP 32768
#define M_ 131072
#define LDH 136   // padded LDS row stride in bf16 elems (272B, breaks bank conflicts)

typedef short bf16x8 __attribute__((ext_vector_type(8)));
typedef float f32x4 __attribute__((ext_vector_type(4)));

static __device__ __forceinline__ ushort f2bf(float x) {
    union { float f; unsigned int u; } v; v.f = x;
    unsigned int r = v.u + 0x7FFFu + ((v.u >> 16) & 1u);
    return (ushort)(r >> 16);
}
static __device__ __forceinline__ float elu1(float x) {
    return x > 0.f ? x : (__expf(x) - 1.f);
}

// ---------------- k1: U/V GEMM + col partials; blocks >=576 do weight pre-swizzle (old k0) ----------------
__global__ __launch_bounds__(128) void k1_uv(const float* __restrict__ flig,
        const float* __restrict__ frec, const float* __restrict__ W1, const float* __restrict__ b1,
        const float* __restrict__ Wc1, const float* __restrict__ Wpi,
        const float* __restrict__ Wsig, const float* __restrict__ Wmu,
        float* __restrict__ U, float* __restrict__ V,
        float* __restrict__ partS, float* __restrict__ partS2,
        ushort* __restrict__ wB, ushort* __restrict__ wBg) {
    __shared__ float fr[8][128];
    int bid = blockIdx.x, c = threadIdx.x;
    if (bid >= 576) {   // weight pre-swizzle path (128 blocks x 128 threads = 16384)
        int idx = (bid - 576) * 128 + c;
        {
            int j = idx & 7, lane = (idx >> 3) & 63, ks = (idx >> 9) & 3, ni = idx >> 11;
            int lrow = lane & 15, kgrp = lane >> 4;
            int n = ni * 16 + lrow, k = ks * 32 + kgrp * 8 + j;
            wB[idx] = f2bf(Wc1[k * HID + n]);
        }
        if (idx < 4096) {
            int j = idx & 7, lane = (idx >> 3) & 63, ks = (idx >> 9) & 3, ni = (idx >> 11) & 1;
            int lrow = lane & 15, kgrp = lane >> 4;
            int n = ni * 16 + lrow, k = ks * 32 + kgrp * 8 + j;
            float wv = 0.f;
            if (n < 10) wv = Wpi[k * KM + n];
            else if (n < 20) wv = Wsig[k * KM + (n - 10)];
            else if (n < 30) wv = Wmu[k * KM + (n - 20)];
            wBg[idx] = f2bf(wv);
        }
        return;
    }
    const float* feat; const float* Wb; float* outp; float bias;
    if (bid < 64) {
        int rowbase = bid * 8;
        feat = flig + rowbase * FD; Wb = W1; outp = U + rowbase * HID; bias = b1[c];
    } else {
        int rowbase = (bid - 64) * 8;
        feat = frec + rowbase * FD; Wb = W1 + FD * HID; outp = V + rowbase * HID; bias = 0.f;
    }
    #pragma unroll
    for (int rr = 0; rr < 8; rr++) fr[rr][c] = feat[rr * FD + c];
    __syncthreads();
    float acc[8];
    #pragma unroll
    for (int rr = 0; rr < 8; rr++) acc[rr] = bias;
    #pragma unroll 4
    for (int k = 0; k < FD; k++) {
        float wv = Wb[k * HID + c];
        #pragma unroll
        for (int rr = 0; rr < 8; rr++) acc[rr] += fr[rr][k] * wv;
    }
    float su = 0.f, su2 = 0.f;
    #pragma unroll
    for (int rr = 0; rr < 8; rr++) {
        outp[rr * HID + c] = acc[rr];
        su += acc[rr]; su2 += acc[rr] * acc[rr];
    }
    partS[bid * 128 + c] = su;
    partS2[bid * 128 + c] = su2;
}

// ---------------- k2: fused BN1 stats reduce + finalize (grid 1 x 1024) ----------------
__global__ __launch_bounds__(1024) void k2_bn1(const float* __restrict__ partS, const float* __restrict__ partS2,
        const float* __restrict__ g1, const float* __restrict__ beta1,
        float* __restrict__ scale1, float* __restrict__ shift1) {
    __shared__ float sU[8][128], sU2[8][128], sV[8][128], sV2[8][128];
    int t = threadIdx.x, c = t & 127, b = t >> 7;
    float su = 0.f, su2 = 0.f;
    #pragma unroll
    for (int j = 0; j < 8; j++) { int row = b * 8 + j; su += partS[row * 128 + c]; su2 += partS2[row * 128 + c]; }
    float sv = 0.f, sv2 = 0.f;
    for (int j = 0; j < 64; j++) { int row = 64 + b * 64 + j; sv += partS[row * 128 + c]; sv2 += partS2[row * 128 + c]; }
    sU[b][c] = su; sU2[b][c] = su2; sV[b][c] = sv; sV2[b][c] = sv2;
    __syncthreads();
    if (t < 128) {
        float sum = 0.f, ssq = 0.f;
        #pragma unroll
        for (int bb = 0; bb < 8; bb++) {
            float s_ = sU[bb][t], v_ = sV[bb][t];
            sum += (float)NR * s_ + (float)NL * v_;
            ssq += (float)NR * sU2[bb][t] + 2.f * s_ * v_ + (float)NL * sV2[bb][t];
        }
        float inv = 1.f / (float)P_;
        float mean = sum * inv;
        float var = ssq * inv - mean * mean;
        float sc = g1[t] * rsqrtf(var + 1e-5f);
        scale1[t] = sc; shift1[t] = beta1[t] - mean * sc;
    }
}

// ---------------- k_sg: MERGED — blocks 0..511 = MDN (k6), blocks 512..767 = sampled BN2 stats (k3s) ----------------
__global__ __launch_bounds__(256) void k_sg(const int* __restrict__ mask,
        const float* __restrict__ U, const float* __restrict__ V,
        const float* __restrict__ scale1, const float* __restrict__ shift1,
        const ushort* __restrict__ wB, const ushort* __restrict__ wBg, const float* __restrict__ bc1,
        const float* __restrict__ bpi, const float* __restrict__ bsig, const float* __restrict__ bmu,
        const float* __restrict__ posl, const float* __restrict__ posr,
        float* __restrict__ out_logpi, float* __restrict__ out_sigma, float* __restrict__ out_mu,
        float* __restrict__ mdn_psum, float* __restrict__ mdn_pcnt,
        float* __restrict__ bn2s, float* __restrict__ bn2s2) {
    __shared__ ushort hT[256 * LDH];            // 69632 B (k3s path uses first 128 rows)
    __shared__ int midx[256];
    __shared__ float mdnv[256];
    __shared__ int mdnb[256];
    __shared__ float psLds[8][8], pcLds[8][8];
    int t = threadIdx.x;
    int w = t >> 6, lane = t & 63, lrow = lane & 15, kgrp = lane >> 4;
    int c8 = (t & 15) * 8, rg = t >> 4;
    float4 sc0 = *(const float4*)&scale1[c8], sc1 = *(const float4*)&scale1[c8 + 4];
    float4 sh0 = *(const float4*)&shift1[c8], sh1 = *(const float4*)&shift1[c8 + 4];

    if (blockIdx.x < 512) {
        // ================= MDN path =================
        float* stageF = (float*)hT;
        float* zl   = stageF;                    // 256*33 = 8448 floats
        float* bufA = stageF + 8448;
        float* bufB = stageF + 11008;
        float* bufC = stageF + 13568;            // ends 16128 floats = 64512 B
        int bid = blockIdx.x;
        int m0 = bid * 256;
        midx[t] = mask[m0 + t];
        __syncthreads();
        #pragma unroll
        for (int rr = rg; rr < 256; rr += 16) {
            int i = midx[rr];
            int bl = i >> 9, b = i >> 15, r = i & 511;
            const float* up = &U[bl * HID + c8];
            const float* vp = &V[(b * NR + r) * HID + c8];
            float4 u0 = *(const float4*)up, u1 = *(const float4*)(up + 4);
            float4 v0 = *(const float4*)vp, v1 = *(const float4*)(vp + 4);
            union { bf16x8 v; ushort u[8]; } o;
            o.u[0] = f2bf(elu1(fmaf(u0.x + v0.x, sc0.x, sh0.x)));
            o.u[1] = f2bf(elu1(fmaf(u0.y + v0.y, sc0.y, sh0.y)));
            o.u[2] = f2bf(elu1(fmaf(u0.z + v0.z, sc0.z, sh0.z)));
            o.u[3] = f2bf(elu1(fmaf(u0.w + v0.w, sc0.w, sh0.w)));
            o.u[4] = f2bf(elu1(fmaf(u1.x + v1.x, sc1.x, sh1.x)));
            o.u[5] = f2bf(elu1(fmaf(u1.y + v1.y, sc1.y, sh1.y)));
            o.u[6] = f2bf(elu1(fmaf(u1.z + v1.z, sc1.z, sh1.z)));
            o.u[7] = f2bf(elu1(fmaf(u1.w + v1.w, sc1.w, sh1.w)));
            *(bf16x8*)&hT[rr * LDH + c8] = o.v;
        }
        __syncthreads();
        int wrow = w * 64;
        f32x4 acc[4][2];
        #pragma unroll
        for (int m = 0; m < 4; m++) { acc[m][0] = (f32x4){0,0,0,0}; acc[m][1] = (f32x4){0,0,0,0}; }
        const bf16x8* wBv = (const bf16x8*)wBg;
        bf16x8 Bg[2][4];
        #pragma unroll
        for (int nil = 0; nil < 2; nil++)
            #pragma unroll
            for (int ks = 0; ks < 4; ks++)
                Bg[nil][ks] = wBv[(nil * 4 + ks) * 64 + lane];
        #pragma unroll
        for (int m = 0; m < 4; m++) {
            #pragma unroll
            for (int ks = 0; ks < 4; ks++) {
                bf16x8 a = *(const bf16x8*)&hT[(wrow + m * 16 + lrow) * LDH + ks * 32 + kgrp * 8];
                acc[m][0] = __builtin_amdgcn_mfma_f32_16x16x32_bf16(a, Bg[0][ks], acc[m][0], 0, 0, 0);
                acc[m][1] = __builtin_amdgcn_mfma_f32_16x16x32_bf16(a, Bg[1][ks], acc[m][1], 0, 0, 0);
            }
        }
        __syncthreads();   // all hT reads done before zl alias writes
        #pragma unroll
        for (int m = 0; m < 4; m++)
            #pragma unroll
            for (int nil = 0; nil < 2; nil++)
                #pragma unroll
                for (int reg = 0; reg < 4; reg++) {
                    int row = wrow + m * 16 + kgrp * 4 + reg;
                    zl[row * 33 + nil * 16 + lrow] = acc[m][nil][reg];
                }
        __syncthreads();
        {
            float zv[30];
            #pragma unroll
            for (int j = 0; j < 30; j++) zv[j] = zl[t * 33 + j];
            float lp[10], mx = -1e30f;
            #pragma unroll
            for (int j = 0; j < 10; j++) { lp[j] = zv[j] + bpi[j]; mx = fmaxf(mx, lp[j]); }
            float se = 0.f;
            #pragma unroll
            for (int j = 0; j < 10; j++) se += __expf(lp[j] - mx);
            float lse = mx + __logf(se);
            #pragma unroll
            for (int j = 0; j < 10; j++) lp[j] -= lse;
            float sg[10], muv[10];
            #pragma unroll
            for (int j = 0; j < 10; j++) sg[j] = elu1(zv[10 + j] + bsig[j]) + 1.1f;
            #pragma unroll
            for (int j = 0; j < 10; j++) muv[j] = elu1(zv[20 + j] + bmu[j]) + 1.0f;
            int i = midx[t];
            int bl = i >> 9, b = i >> 15, r = i & 511;
            float dx = posl[bl * 3]     - posr[(b * NR + r) * 3];
            float dy = posl[bl * 3 + 1] - posr[(b * NR + r) * 3 + 1];
            float dz = posl[bl * 3 + 2] - posr[(b * NR + r) * 3 + 2];
            float y = sqrtf(dx * dx + dy * dy + dz * dz);
            float tt[10], mm = -1e30f;
            #pragma unroll
            for (int j = 0; j < 10; j++) {
                float q = (y - muv[j]) / sg[j];
                float llv = -0.5f * q * q - __logf(sg[j]) - 0.91893853320467274f;
                tt[j] = lp[j] + llv; mm = fmaxf(mm, tt[j]);
            }
            float s2e = 0.f;
            #pragma unroll
            for (int j = 0; j < 10; j++) s2e += __expf(tt[j] - mm);
            float mdn = -(mm + __logf(s2e));
            #pragma unroll
            for (int j = 0; j < 10; j++) { bufA[t * 10 + j] = lp[j]; bufB[t * 10 + j] = sg[j]; bufC[t * 10 + j] = muv[j]; }
            mdnv[t] = mdn; mdnb[t] = b;
        }
        __syncthreads();
        {
            float4* oA = (float4*)&out_logpi[m0 * 10];
            float4* oB = (float4*)&out_sigma[m0 * 10];
            float4* oC = (float4*)&out_mu[m0 * 10];
            const float4* bA = (const float4*)bufA;
            const float4* bB = (const float4*)bufB;
            const float4* bC = (const float4*)bufC;
            #pragma unroll
            for (int i4 = t; i4 < 640; i4 += 256) { oA[i4] = bA[i4]; oB[i4] = bB[i4]; oC[i4] = bC[i4]; }
        }
        if (t < 64) {   // deterministic fixed-order partial sums: 8 chunks x 8 batches
            int bb = t & 7, chunk = t >> 3;
            float s = 0.f; int cnt = 0;
            for (int rr = chunk * 32; rr < chunk * 32 + 32; rr++)
                if (mdnb[rr] == bb) { s += mdnv[rr]; cnt++; }
            psLds[chunk][bb] = s; pcLds[chunk][bb] = (float)cnt;
        }
        __syncthreads();
        if (t < 8) {
            float s = 0.f, cnt = 0.f;
            #pragma unroll
            for (int chunk = 0; chunk < 8; chunk++) { s += psLds[chunk][t]; cnt += pcLds[chunk][t]; }
            mdn_psum[bid * 8 + t] = s; mdn_pcnt[bid * 8 + t] = cnt;
        }
    } else {
        // ================= sampled BN2 stats path =================
        int bid = blockIdx.x - 512;
        int bl0 = bid * 2, bl1 = bl0 + 1;
        const bf16x8* wBv = (const bf16x8*)wB;
        bf16x8 Bfr[2][4];
        #pragma unroll
        for (int nil = 0; nil < 2; nil++)
            #pragma unroll
            for (int ks = 0; ks < 4; ks++)
                Bfr[nil][ks] = wBv[((w * 2 + nil) * 4 + ks) * 64 + lane];
        float bc1v[2] = { bc1[w * 32 + lrow], bc1[w * 32 + 16 + lrow] };
        float4 uA0 = *(const float4*)&U[bl0 * HID + c8], uA1 = *(const float4*)&U[bl0 * HID + c8 + 4];
        float4 uB0 = *(const float4*)&U[bl1 * HID + c8], uB1 = *(const float4*)&U[bl1 * HID + c8 + 4];
        float4 ubA0, ubA1, ubB0, ubB1;
        ubA0.x = fmaf(uA0.x, sc0.x, sh0.x); ubA0.y = fmaf(uA0.y, sc0.y, sh0.y);
        ubA0.z = fmaf(uA0.z, sc0.z, sh0.z); ubA0.w = fmaf(uA0.w, sc0.w, sh0.w);
        ubA1.x = fmaf(uA1.x, sc1.x, sh1.x); ubA1.y = fmaf(uA1.y, sc1.y, sh1.y);
        ubA1.z = fmaf(uA1.z, sc1.z, sh1.z); ubA1.w = fmaf(uA1.w, sc1.w, sh1.w);
        ubB0.x = fmaf(uB0.x, sc0.x, sh0.x); ubB0.y = fmaf(uB0.y, sc0.y, sh0.y);
        ubB0.z = fmaf(uB0.z, sc0.z, sh0.z); ubB0.w = fmaf(uB0.w, sc0.w, sh0.w);
        ubB1.x = fmaf(uB1.x, sc1.x, sh1.x); ubB1.y = fmaf(uB1.y, sc1.y, sh1.y);
        ubB1.z = fmaf(uB1.z, sc1.z, sh1.z); ubB1.w = fmaf(uB1.w, sc1.w, sh1.w);
        int vbatch = (bl0 >> 6) << 9;
        #pragma unroll
        for (int k = 0; k < 8; k++) {
            int rr = rg + k * 16;
            int j = rr & 63;
            const float* vp = &V[(vbatch + j * 8) * HID + c8];
            float4 v0 = *(const float4*)vp, v1 = *(const float4*)(vp + 4);
            float4 ub0 = (k < 4) ? ubA0 : ubB0;
            float4 ub1 = (k < 4) ? ubA1 : ubB1;
            union { bf16x8 v; ushort u[8]; } o;
            o.u[0] = f2bf(elu1(fmaf(v0.x, sc0.x, ub0.x)));
            o.u[1] = f2bf(elu1(fmaf(v0.y, sc0.y, ub0.y)));
            o.u[2] = f2bf(elu1(fmaf(v0.z, sc0.z, ub0.z)));
            o.u[3] = f2bf(elu1(fmaf(v0.w, sc0.w, ub0.w)));
            o.u[4] = f2bf(elu1(fmaf(v1.x, sc1.x, ub1.x)));
            o.u[5] = f2bf(elu1(fmaf(v1.y, sc1.y, ub1.y)));
            o.u[6] = f2bf(elu1(fmaf(v1.z, sc1.z, ub1.z)));
            o.u[7] = f2bf(elu1(fmaf(v1.w, sc1.w, ub1.w)));
            *(bf16x8*)&hT[rr * LDH + c8] = o.v;
        }
        __syncthreads();
        f32x4 acc[8][2];
        #pragma unroll
        for (int m = 0; m < 8; m++) { acc[m][0] = (f32x4){0,0,0,0}; acc[m][1] = (f32x4){0,0,0,0}; }
        #pragma unroll
        for (int m = 0; m < 8; m++) {
            #pragma unroll
            for (int ks = 0; ks < 4; ks++) {
                bf16x8 a = *(const bf16x8*)&hT[(m * 16 + lrow) * LDH + ks * 32 + kgrp * 8];
                acc[m][0] = __builtin_amdgcn_mfma_f32_16x16x32_bf16(a, Bfr[0][ks], acc[m][0], 0, 0, 0);
                acc[m][1] = __builtin_amdgcn_mfma_f32_16x16x32_bf16(a, Bfr[1][ks], acc[m][1], 0, 0, 0);
            }
        }
        float s[2] = {0.f, 0.f}, s2[2] = {0.f, 0.f};
        #pragma unroll
        for (int nil = 0; nil < 2; nil++)
            #pragma unroll
            for (int reg = 0; reg < 4; reg++)
                #pragma unroll
                for (int m = 0; m < 8; m++) {
                    float vv = acc[m][nil][reg] + bc1v[nil];
                    s[nil] += vv; s2[nil] += vv * vv;
                }
        #pragma unroll
        for (int nil = 0; nil < 2; nil++) {
            s[nil] += __shfl_xor(s[nil], 16);  s[nil] += __shfl_xor(s[nil], 32);
            s2[nil] += __shfl_xor(s2[nil], 16); s2[nil] += __shfl_xor(s2[nil], 32);
        }
        if (lane < 16) {
            bn2s[bid * 128 + w * 32 + lane]       = s[0];
            bn2s[bid * 128 + w * 32 + 16 + lane]  = s[1];
            bn2s2[bid * 128 + w * 32 + lane]      = s2[0];
            bn2s2[bid * 128 + w * 32 + 16 + lane] = s2[1];
        }
    }
}

// ---------------- k4: sampled-BN2 finalize + prob segment-mean (grid 1 x 1024) ----------------
__global__ __launch_bounds__(1024) void k4_bn2(const float* __restrict__ bn2s, const float* __restrict__ bn2s2,
        const float* __restrict__ gc, const float* __restrict__ betac, const float* __restrict__ bc1,
        const float* __restrict__ psum, const float* __restrict__ pcnt,
        float* __restrict__ Af, float* __restrict__ Bf2, float* __restrict__ prob) {
    __shared__ float rs[8][128], rs2[8][128];
    __shared__ float prs[8][128], prc[8][128];
    int t = threadIdx.x, c = t & 127, g = t >> 7;
    float s = 0.f, s2 = 0.f;
    for (int j = 0; j < 32; j++) { int row = g * 32 + j; s += bn2s[row * 128 + c]; s2 += bn2s2[row * 128 + c]; }
    rs[g][c] = s; rs2[g][c] = s2;
    // prob partials: batch g, thread c sums rows c, c+128, c+256, c+384
    float ps = 0.f, pc = 0.f;
    #pragma unroll
    for (int k = 0; k < 4; k++) { int row = c + k * 128; ps += psum[row * 8 + g]; pc += pcnt[row * 8 + g]; }
    prs[g][c] = ps; prc[g][c] = pc;
    __syncthreads();
    for (int off = 64; off > 0; off >>= 1) {
        if (c < off) { prs[g][c] += prs[g][c + off]; prc[g][c] += prc[g][c + off]; }
        __syncthreads();
    }
    if (c == 0) prob[g] = prs[g][0] / fmaxf(prc[g][0], 1.f);
    if (t < 128) {
        float ss = 0.f, ss2 = 0.f;
        #pragma unroll
        for (int gg = 0; gg < 8; gg++) { ss += rs[gg][t]; ss2 += rs2[gg][t]; }
        float inv = 1.f / (float)NSAMP;
        float mean = ss * inv, var = ss2 * inv - mean * mean;
        float sc = gc[t] * rsqrtf(var + 1e-5f);
        Af[t] = sc;
        Bf2[t] = (bc1[t] - mean) * sc + betac[t];
    }
}

// ---------------- k3f: fused GEMM + contact epilogue, one 128-pair tile per block (grid 2048) ----------------
__global__ __launch_bounds__(256, 2) void k3f_gemm(const float* __restrict__ U, const float* __restrict__ V,
        const ushort* __restrict__ wB,
        const float* __restrict__ scale1, const float* __restrict__ shift1,
        const float* __restrict__ Af, const float* __restrict__ Bf2,
        const float* __restrict__ Wc2, const float* __restrict__ bc2,
        const float* __restrict__ posl, const float* __restrict__ posr,
        float* __restrict__ outc, float* __restrict__ outt) {
    __shared__ ushort hT[128 * LDH];     // 34816 B
    __shared__ float part[4][128];       // 2048 B -> 36.9 KB => 4 blocks/CU
    int bid = blockIdx.x, t = threadIdx.x;
    int bl = bid >> 2, it = bid & 3;
    int w = t >> 6, lane = t & 63, lrow = lane & 15, kgrp = lane >> 4;
    const bf16x8* wBv = (const bf16x8*)wB;
    bf16x8 Bfr[2][4];
    #pragma unroll
    for (int nil = 0; nil < 2; nil++)
        #pragma unroll
        for (int ks = 0; ks < 4; ks++)
            Bfr[nil][ks] = wBv[((w * 2 + nil) * 4 + ks) * 64 + lane];
    float av[2], bv[2], wv[2];
    #pragma unroll
    for (int nil = 0; nil < 2; nil++) {
        int c = w * 32 + nil * 16 + lrow;
        av[nil] = Af[c]; bv[nil] = Bf2[c]; wv[nil] = Wc2[c];
    }
    float bc2v = bc2[0];
    int c8 = (t & 15) * 8, rg = t >> 4;
    float4 sc0 = *(const float4*)&scale1[c8], sc1 = *(const float4*)&scale1[c8 + 4];
    float4 sh0 = *(const float4*)&shift1[c8], sh1 = *(const float4*)&shift1[c8 + 4];
    float4 u0 = *(const float4*)&U[bl * HID + c8];
    float4 u1 = *(const float4*)&U[bl * HID + c8 + 4];
    float4 ub0, ub1;
    ub0.x = fmaf(u0.x, sc0.x, sh0.x); ub0.y = fmaf(u0.y, sc0.y, sh0.y);
    ub0.z = fmaf(u0.z, sc0.z, sh0.z); ub0.w = fmaf(u0.w, sc0.w, sh0.w);
    ub1.x = fmaf(u1.x, sc1.x, sh1.x); ub1.y = fmaf(u1.y, sc1.y, sh1.y);
    ub1.z = fmaf(u1.z, sc1.z, sh1.z); ub1.w = fmaf(u1.w, sc1.w, sh1.w);
    int vtile = ((bl >> 6) << 9) + it * 128;
    // stage h tile
    #pragma unroll
    for (int rr = rg; rr < 128; rr += 16) {
        const float* vp = &V[(vtile + rr) * HID + c8];
        float4 v0 = *(const float4*)vp, v1 = *(const float4*)(vp + 4);
        union { bf16x8 v; ushort u[8]; } o;
        o.u[0] = f2bf(elu1(fmaf(v0.x, sc0.x, ub0.x)));
        o.u[1] = f2bf(elu1(fmaf(v0.y, sc0.y, ub0.y)));
        o.u[2] = f2bf(elu1(fmaf(v0.z, sc0.z, ub0.z)));
        o.u[3] = f2bf(elu1(fmaf(v0.w, sc0.w, ub0.w)));
        o.u[4] = f2bf(elu1(fmaf(v1.x, sc1.x, ub1.x)));
        o.u[5] = f2bf(elu1(fmaf(v1.y, sc1.y, ub1.y)));
        o.u[6] = f2bf(elu1(fmaf(v1.z, sc1.z, ub1.z)));
        o.u[7] = f2bf(elu1(fmaf(v1.w, sc1.w, ub1.w)));
        *(bf16x8*)&hT[rr * LDH + c8] = o.v;
    }
    __syncthreads();
    f32x4 acc[8][2];
    #pragma unroll
    for (int m = 0; m < 8; m++) { acc[m][0] = (f32x4){0,0,0,0}; acc[m][1] = (f32x4){0,0,0,0}; }
    #pragma unroll
    for (int m = 0; m < 8; m++) {
        #pragma unroll
        for (int ks = 0; ks < 4; ks++) {
            bf16x8 a = *(const bf16x8*)&hT[(m * 16 + lrow) * LDH + ks * 32 + kgrp * 8];
            acc[m][0] = __builtin_amdgcn_mfma_f32_16x16x32_bf16(a, Bfr[0][ks], acc[m][0], 0, 0, 0);
            acc[m][1] = __builtin_amdgcn_mfma_f32_16x16x32_bf16(a, Bfr[1][ks], acc[m][1], 0, 0, 0);
        }
    }
    // fused epilogue: relu(acc*Af + Bf2)·Wc2, per-wave partial, 16-lane shfl reduce
    #pragma unroll
    for (int reg = 0; reg < 4; reg++) {
        float pr[8];
        #pragma unroll
        for (int m = 0; m < 8; m++) pr[m] = 0.f;
        #pragma unroll
        for (int nil = 0; nil < 2; nil++)
            #pragma unroll
            for (int m = 0; m < 8; m++) {
                float x = fmaf(acc[m][nil][reg], av[nil], bv[nil]);
                pr[m] += fmaxf(x, 0.f) * wv[nil];
            }
        #pragma unroll
        for (int m = 0; m < 8; m++) {
            pr[m] += __shfl_xor(pr[m], 1); pr[m] += __shfl_xor(pr[m], 2);
            pr[m] += __shfl_xor(pr[m], 4); pr[m] += __shfl_xor(pr[m], 8);
        }
        if (lrow == 0) {
            #pragma unroll
            for (int m = 0; m < 8; m++) part[w][m * 16 + kgrp * 4 + reg] = pr[m];
        }
    }
    __syncthreads();
    if (t < 128) {
        int row = bid * 128 + t;
        outc[row] = part[0][t] + part[1][t] + part[2][t] + part[3][t] + bc2v;
        int pbl = row >> 9, pb = row >> 15, pr_ = row & 511;
        float dx = posl[pbl * 3]     - posr[(pb * NR + pr_) * 3];
        float dy = posl[pbl * 3 + 1] - posr[(pb * NR + pr_) * 3 + 1];
        float dz = posl[pbl * 3 + 2] - posr[(pb * NR + pr_) * 3 + 2];
        float y = sqrtf(dx * dx + dy * dy + dz * dz);
        outt[row] = (y < 8.0f) ? 1.0f : 0.0f;
    }
}

extern "C" void kernel_launch(void* const* d_in, const int* in_sizes, int n_in,
                              void* d_out, int out_size, void* d_ws, size_t ws_size,
                              hipStream_t stream) {
    const float* flig  = (const float*)d_in[0];
    const float* posl  = (const float*)d_in[1];
    const float* frec  = (const float*)d_in[3];
    const float* posr  = (const float*)d_in[4];
    const int*   mask  = (const int*)d_in[6];
    const float* W1    = (const float*)d_in[7];
    const float* b1    = (const float*)d_in[8];
    const float* g1    = (const float*)d_in[9];
    const float* beta1 = (const float*)d_in[10];
    const float* Wpi   = (const float*)d_in[11];
    const float* bpi   = (const float*)d_in[12];
    const float* Wsig  = (const float*)d_in[13];
    const float* bsig  = (const float*)d_in[14];
    const float* Wmu   = (const float*)d_in[15];
    const float* bmu   = (const float*)d_in[16];
    const float* Wc1   = (const float*)d_in[17];
    const float* bc1   = (const float*)d_in[18];
    const float* gc    = (const float*)d_in[19];
    const float* betac = (const float*)d_in[20];
    const float* Wc2   = (const float*)d_in[21];
    const float* bc2   = (const float*)d_in[22];

    float* ws = (float*)d_ws;
    float* U      = ws;                 // 65536
    float* V      = ws + 65536;         // 524288 (end 589824)
    float* scale1 = ws + 589824;        // 128
    float* shift1 = ws + 589952;
    float* Af     = ws + 590080;
    float* Bf2    = ws + 590208;        // (end 590336)
    ushort* wB    = (ushort*)(ws + 590336);   // 16384 bf16 = 8192 f (end 598528)
    ushort* wBg   = (ushort*)(ws + 598528);   // 4096 bf16 = 2048 f (end 600576)
    float* bn2s   = ws + 600576;        // 256*128 = 32768 (end 633344)
    float* bn2s2  = ws + 633344;        // (end 666112)
    float* psum   = ws + 666112;        // 4096 (end 670208)
    float* pcnt   = ws + 670208;        // (end 674304)
    float* partS  = ws + 674304;        // 576*128 = 73728 (end 748032)
    float* partS2 = ws + 748032;        // (end 821760)

    float* out = (float*)d_out;
    float* out_logpi   = out;
    float* out_sigma   = out + 1310720;
    float* out_mu      = out + 2621440;
    float* out_prob    = out + 3932160;
    float* out_contact = out + 3932168;
    float* out_truth   = out + 4194312;

    k1_uv<<<dim3(704), dim3(128), 0, stream>>>(flig, frec, W1, b1, Wc1, Wpi, Wsig, Wmu,
        U, V, partS, partS2, wB, wBg);
    k2_bn1<<<dim3(1), dim3(1024), 0, stream>>>(partS, partS2, g1, beta1, scale1, shift1);
    k_sg<<<dim3(768), dim3(256), 0, stream>>>(mask, U, V, scale1, shift1, wB, wBg, bc1,
        bpi, bsig, bmu, posl, posr, out_logpi, out_sigma, out_mu, psum, pcnt, bn2s, bn2s2);
    k4_bn2<<<dim3(1), dim3(1024), 0, stream>>>(bn2s, bn2s2, gc, betac, bc1, psum, pcnt, Af, Bf2, out_prob);
    k3f_gemm<<<dim3(2048), dim3(256), 0, stream>>>(U, V, wB, scale1, shift1, Af, Bf2, Wc2, bc2,
        posl, posr, out_contact, out_truth);
}